// Round 21
// baseline (435.196 us; speedup 1.0000x reference)
//
#include <hip/hip_runtime.h>
#include <cstdint>
#include <cstddef>

#define TT 4
#define BB 8
#define CC 256
#define NN 1024
#define HEADS 8
#define DD 32
#define FIXCAP 262144u

typedef __attribute__((ext_vector_type(4))) float f32x4;
typedef __attribute__((ext_vector_type(8))) short s16x8;
typedef unsigned short u16;
typedef unsigned int   u32;

__device__ __forceinline__ u16 bf16_rne(float x) {
    u32 u = __float_as_uint(x);
    return (u16)((u + 0x7FFFu + ((u >> 16) & 1u)) >> 16);
}
__device__ __forceinline__ float bf16f(u16 h) {
    return __uint_as_float(((u32)h) << 16);
}

__global__ __launch_bounds__(64) void zero_counters(u32* c) {
    if (threadIdx.x < 4) c[threadIdx.x] = 0;
}

// Fragment-major index for a [R][K] bf16 plane:
//   FM(r,k) = ((r>>4)*(K/32) + (k>>5))*512 + ((k>>3)&3)*128 + (r&15)*8 + (k&7)

// ---- prep: weights f32 [O][K] -> FM hi/lo bf16 planes ----
template<int OO, int CIN>
__global__ __launch_bounds__(256) void prep_split_fm(
    const float* __restrict__ src, u16* __restrict__ h, u16* __restrict__ l)
{
    const int id = blockIdx.x * 256 + threadIdx.x;
    if (id >= OO * CIN / 8) return;
    const int o = id / (CIN / 8), kq = id % (CIN / 8);
    const float* p = src + (size_t)o * CIN + kq * 8;
    s16x8 hh, ll;
#pragma unroll
    for (int e = 0; e < 8; ++e) {
        float f = p[e];
        u16 hb = bf16_rne(f);
        hh[e] = (short)hb;
        ll[e] = (short)bf16_rne(f - bf16f(hb));
    }
    const int lane = (kq & 3) * 16 + (o & 15);
    const size_t dst = (((size_t)(o >> 4) * (CIN / 32) + (kq >> 2)) * 64 + lane) * 8;
    *(s16x8*)&h[dst] = hh;
    *(s16x8*)&l[dst] = ll;
}

// ---- transpose+split: f32 [m][K][N] -> FM hi/lo planes over [N rows][K cols] ----
template<int K, int N>
__global__ __launch_bounds__(256) void trans_split_fm(
    const float* __restrict__ src, u16* __restrict__ dh, u16* __restrict__ dl)
{
    __shared__ float tile[64][65];
    const int tid = threadIdx.x;
    const int n0 = blockIdx.x * 64, k0 = blockIdx.y * 64, m = blockIdx.z;
    for (int i = tid; i < 4096; i += 256) {
        int kk = i >> 6, nn = i & 63;
        tile[kk][nn] = src[((size_t)m * K + k0 + kk) * N + n0 + nn];
    }
    __syncthreads();
    const size_t plane = (size_t)m * (N / 16) * (K / 32) * 512;
    for (int it = tid; it < 512; it += 256) {
        const int nn = it >> 3, kq = it & 7;
        s16x8 hh, ll;
#pragma unroll
        for (int e = 0; e < 8; ++e) {
            float f = tile[kq * 8 + e][nn];
            u16 hb = bf16_rne(f);
            hh[e] = (short)hb;
            ll[e] = (short)bf16_rne(f - bf16f(hb));
        }
        const int n = n0 + nn;
        const int ks = (k0 >> 5) + (kq >> 2), lk = kq & 3;
        const size_t dst = plane + (((size_t)(n >> 4) * (K / 32) + ks) * 64
                                    + lk * 16 + (n & 15)) * 8;
        *(s16x8*)&dh[dst] = hh;
        *(s16x8*)&dl[dst] = ll;
    }
}

// ---- transpose bf16 [m][K][N] -> FM plane over [N rows][K cols] ----
template<int K, int N>
__global__ __launch_bounds__(256) void trans_u16_fm(
    const u16* __restrict__ src, u16* __restrict__ dst)
{
    __shared__ u16 tile[64][72];
    const int tid = threadIdx.x;
    const int n0 = blockIdx.x * 64, k0 = blockIdx.y * 64, m = blockIdx.z;
    for (int i = tid; i < 4096; i += 256) {
        int kk = i >> 6, nn = i & 63;
        tile[kk][nn] = src[((size_t)m * K + k0 + kk) * N + n0 + nn];
    }
    __syncthreads();
    const size_t plane = (size_t)m * (N / 16) * (K / 32) * 512;
    for (int it = tid; it < 512; it += 256) {
        const int nn = it >> 3, kq = it & 7;
        s16x8 hh;
#pragma unroll
        for (int e = 0; e < 8; ++e) hh[e] = (short)tile[kq * 8 + e][nn];
        const int n = n0 + nn;
        const int ks = (k0 >> 5) + (kq >> 2), lk = kq & 3;
        const size_t d = plane + (((size_t)(n >> 4) * (K / 32) + ks) * 64
                                  + lk * 16 + (n & 15)) * 8;
        *(s16x8*)&dst[d] = hh;
    }
}

// ---- per-channel BN constants ----
__global__ __launch_bounds__(256) void prep_bn(
    const float* qbn, const float* kbn, const float* vbn, const float* pbn,
    const float* m1bn, const float* m2bn,
    const float* pb, const float* m1b, const float* m2b,
    float2* __restrict__ bnf, double* __restrict__ bnd)
{
    int c = blockIdx.x * 256 + threadIdx.x;
    if (c >= 2304) return;
    const float* bn; int ch, O; double bi = 0.0;
    if (c < 1024) {
        int s = c >> 8; ch = c & 255; O = 256;
        bn = s == 0 ? qbn : s == 1 ? kbn : s == 2 ? vbn : pbn;
        if (s == 3) bi = (double)pb[ch];
    } else if (c < 2048) { ch = c - 1024; O = 1024; bn = m1bn; bi = (double)m1b[ch]; }
    else                 { ch = c - 2048; O = 256;  bn = m2bn; bi = (double)m2b[ch]; }
    double g = (double)bn[0*O+ch], be = (double)bn[1*O+ch];
    double mu = (double)bn[2*O+ch], var = (double)bn[3*O+ch];
    double sd = g / sqrt(var + 1e-5);
    bnf[c] = make_float2((float)sd, (float)((bi - mu) * sd + be));
    bnd[c] = sd;
}

// ---- conv1x1 + BN + LIF: fragment-major direct-global bf16-split MFMA ----
// B frags double-buffered; A frags loaded per-K-step (W is L2-hot, latency
// covered by 3 waves/SIMD). launch_bounds (256,3): ~140 unified regs fit 170.
// OUT_MODE: 0 bf16 spikes natural [c][n] | 1 f32 +base (proj) |
//           2 bf16 spikes FM-DIRECT (LDS-staged coalesced) | 3 f32 +base
template<bool SPLIT_IN, int CIN, int OUT_MODE, bool TRIPLE, int O>
__global__ __launch_bounds__(256, 3) void conv_kernel(
    const u16* __restrict__ XTH, const u16* __restrict__ XTL,
    const u16* __restrict__ WH0, const u16* __restrict__ WL0,
    const u16* __restrict__ WH1, const u16* __restrict__ WL1,
    const u16* __restrict__ WH2, const u16* __restrict__ WL2,
    const float2* __restrict__ bnf,
    void* __restrict__ O0_, void* __restrict__ O1_, void* __restrict__ O2_,
    const float* __restrict__ base,
    u32* __restrict__ cnt, u32* __restrict__ list)
{
    constexpr float EPS = 3e-4f;
    constexpr u32 OT = TRIPLE ? 12 : O / 64;
    constexpr u32 NWG = OT * 16 * 8;
    constexpr int NS = CIN / 32;
    constexpr u32 KS = (u32)(CIN / 32);
    __shared__ float pre[2 * 64 * 64];

    const int tid  = threadIdx.x;
    const int lane = tid & 63;
    const int wave = tid >> 6;          // == timestep t
    const int lr   = lane & 15;
    const int lk   = lane >> 4;

    const u32 orig = blockIdx.x + OT * (blockIdx.y + 16u * blockIdx.z);
    const u32 flat = (orig & 7u) * (NWG >> 3) + (orig >> 3);
    const u32 otile = flat % OT;
    const u32 rem   = flat / OT;
    const int n0 = (int)(rem & 15u) * 64;
    const int b  = (int)(rem >> 4);

    int o0, sel;
    const u16 *WH, *WL;
    void* Out_;
    if constexpr (TRIPLE) {
        sel = (int)(otile >> 2);
        o0 = (int)(otile & 3) * 64;
        WH = sel==0?WH0:sel==1?WH1:WH2;  WL = sel==0?WL0:sel==1?WL1:WL2;
        Out_ = sel==0?O0_:sel==1?O1_:O2_;
    } else {
        sel = 0; o0 = (int)otile * 64; WH = WH0; WL = WL0; Out_ = O0_;
    }
    const int cofs = sel * 256;

    f32x4 acc[4][4];
#pragma unroll
    for (int mf = 0; mf < 4; ++mf)
#pragma unroll
        for (int nf = 0; nf < 4; ++nf)
            acc[mf][nf] = (f32x4){0.f, 0.f, 0.f, 0.f};

    u32 afm[4], bfm[4];
#pragma unroll
    for (int mf = 0; mf < 4; ++mf)
        afm[mf] = ((u32)(o0 / 16 + mf) * KS) * 512u + (u32)lane * 8u;
    const u32 xplane = (u32)(wave * BB + b) * (u32)(NN / 16) * KS * 512u;
#pragma unroll
    for (int nf = 0; nf < 4; ++nf)
        bfm[nf] = xplane + ((u32)(n0 / 16 + nf) * KS) * 512u + (u32)lane * 8u;

    struct FragB { s16x8 bH[4], bL[4]; };
    FragB g0, g1;

    auto loadB = [&](int ks, FragB& f) {
        const u32 ko = (u32)ks * 512u;
#pragma unroll
        for (int nf = 0; nf < 4; ++nf) {
            f.bH[nf] = *(const s16x8*)&XTH[(size_t)(bfm[nf] + ko)];
            if constexpr (SPLIT_IN)
                f.bL[nf] = *(const s16x8*)&XTL[(size_t)(bfm[nf] + ko)];
        }
    };
    auto computeS = [&](int ks, FragB& f) {
        const u32 ko = (u32)ks * 512u;
        s16x8 aH[4], aL[4];
#pragma unroll
        for (int mf = 0; mf < 4; ++mf) {
            aH[mf] = *(const s16x8*)&WH[(size_t)(afm[mf] + ko)];
            aL[mf] = *(const s16x8*)&WL[(size_t)(afm[mf] + ko)];
        }
        __builtin_amdgcn_s_setprio(1);
#pragma unroll
        for (int mf = 0; mf < 4; ++mf)
#pragma unroll
            for (int nf = 0; nf < 4; ++nf) {
                acc[mf][nf] = __builtin_amdgcn_mfma_f32_16x16x32_bf16(
                    aH[mf], f.bH[nf], acc[mf][nf], 0, 0, 0);
                acc[mf][nf] = __builtin_amdgcn_mfma_f32_16x16x32_bf16(
                    aL[mf], f.bH[nf], acc[mf][nf], 0, 0, 0);
                if constexpr (SPLIT_IN)
                    acc[mf][nf] = __builtin_amdgcn_mfma_f32_16x16x32_bf16(
                        aH[mf], f.bL[nf], acc[mf][nf], 0, 0, 0);
            }
        __builtin_amdgcn_s_setprio(0);
    };

    loadB(0, g0);
#pragma unroll
    for (int ks = 0; ks < NS; ++ks) {
        if ((ks & 1) == 0) {
            if (ks + 1 < NS) loadB(ks + 1, g1);
            computeS(ks, g0);
        } else {
            if (ks + 1 < NS) loadB(ks + 1, g0);
            computeS(ks, g1);
        }
    }

    const int nl = tid & 63;
    const int og = wave;

    auto dump = [&](int slot) {
#pragma unroll
        for (int mf = 0; mf < 4; ++mf)
#pragma unroll
            for (int nf = 0; nf < 4; ++nf)
#pragma unroll
                for (int r = 0; r < 4; ++r)
                    pre[(size_t)(slot * 64 + mf * 16 + lk * 4 + r) * 64
                        + nf * 16 + lr] = acc[mf][nf][r];
    };

    float2 sc[16];
#pragma unroll
    for (int i = 0; i < 16; ++i) sc[i] = bnf[cofs + o0 + og * 16 + i];

    unsigned flags = 0;
    float vst[16];
    u32 spA = 0, spB = 0;   // OUT_MODE 2: spike bits (t0/t1 in A, t2/t3 in B)

    auto do_round = [&](int tbase) {
#pragma unroll
        for (int i = 0; i < 16; ++i) {
            const int o = o0 + og * 16 + i;
            float v = (tbase == 0) ? 0.f : vst[i];
#pragma unroll
            for (int dt = 0; dt < 2; ++dt) {
                const int t = tbase + dt;
                float val = fmaf(pre[(size_t)(dt * 64 + og * 16 + i) * 64 + nl], sc[i].x, sc[i].y);
                v = v + (val - v) * 0.5f;
                if (fabsf(v - 1.0f) < EPS) flags |= (1u << i);
                float s = (v >= 1.0f) ? 1.f : 0.f;
                if constexpr (OUT_MODE == 2) {
                    const u32 bit = (s > 0.5f) ? 1u : 0u;
                    if (tbase == 0) spA |= bit << (dt * 16 + i);
                    else            spB |= bit << (dt * 16 + i);
                } else {
                    const size_t idx = (((size_t)t * BB + b) * O + o) * NN + n0 + nl;
                    if constexpr (OUT_MODE == 0)
                        ((u16*)Out_)[idx] = (s > 0.5f) ? (u16)0x3F80 : (u16)0;
                    else
                        ((float*)Out_)[idx] = base[idx] + s;
                }
                v *= (1.f - s);
            }
            vst[i] = v;
        }
    };

    __syncthreads();
    if (wave < 2) dump(wave);
    __syncthreads();
    do_round(0);
    __syncthreads();
    if (wave >= 2) dump(wave - 2);
    __syncthreads();
    do_round(2);

    if constexpr (OUT_MODE == 2) {
        // stage spikes in LDS (tile-FM layout), then coalesced chunk writes
        __syncthreads();
        u16* lds16 = (u16*)pre;
#pragma unroll
        for (int dt = 0; dt < 2; ++dt)
#pragma unroll
            for (int i = 0; i < 16; ++i) {
                const int ol = og * 16 + i;
                const int loc = ((nl >> 4) * 2 + (ol >> 5)) * 512
                              + ((ol >> 3) & 3) * 128 + (nl & 15) * 8 + (ol & 7);
                lds16[dt * 4096 + loc] =
                    ((spA >> (dt * 16 + i)) & 1u) ? (u16)0x3F80 : (u16)0;
                lds16[(2 + dt) * 4096 + loc] =
                    ((spB >> (dt * 16 + i)) & 1u) ? (u16)0x3F80 : (u16)0;
            }
        __syncthreads();
        constexpr u32 KO = (u32)(O / 32);
        for (int idx2 = tid; idx2 < 2048; idx2 += 256) {
            const int t = idx2 >> 9, rem2 = idx2 & 511;
            const int c = rem2 >> 6, pos = (rem2 & 63) * 8;
            const int nt = c >> 1, ob = c & 1;
            const size_t gb = (((size_t)(t * BB + b) * (NN / 16) + (n0 / 16 + nt)) * KO
                               + (o0 / 32 + ob)) * 512 + pos;
            *(s16x8*)&((u16*)Out_)[gb] = *(const s16x8*)&lds16[t * 4096 + c * 512 + pos];
        }
    }

    if (flags) {
#pragma unroll 1
        for (int i = 0; i < 16; ++i) {
            if (!(flags & (1u << i))) continue;
            const int o = o0 + og * 16 + i;
            const u32 ent = ((u32)sel << 23) | ((u32)b << 20) | ((u32)o << 10)
                          | (u32)(n0 + nl);
            const u32 idx = atomicAdd(cnt, 1u);
            if (idx < FIXCAP) list[idx] = ent;
        }
    }
}

// ---- exact f64 fixup: one wave per flagged column, lane-parallel K ----
template<bool XE_BF16, bool XE_FM, int CIN, int OUT_MODE, int O>
__global__ __launch_bounds__(64) void fixup_kernel(
    const u32* __restrict__ cnt, const u32* __restrict__ list,
    const void* __restrict__ Xe_,
    const float* __restrict__ Wx0, const float* __restrict__ Wx1,
    const float* __restrict__ Wx2,
    const float* __restrict__ bnr0, const float* __restrict__ bnr1,
    const float* __restrict__ bnr2, const float* __restrict__ bias,
    const double* __restrict__ bnd,
    void* __restrict__ O0_, void* __restrict__ O1_, void* __restrict__ O2_,
    const float* __restrict__ base)
{
    const u32 c0 = *cnt;
    const u32 count = c0 > FIXCAP ? FIXCAP : c0;
    const int lane = threadIdx.x;
    for (u32 e = blockIdx.x; e < count; e += gridDim.x) {
        const u32 ent = list[e];
        const int n = (int)(ent & 1023u);
        const int o = (int)((ent >> 10) & 1023u);
        const int b = (int)((ent >> 20) & 7u);
        const int sel = (int)(ent >> 23);
        const float* Wx  = sel == 0 ? Wx0  : (sel == 1 ? Wx1  : Wx2);
        const float* bnr = sel == 0 ? bnr0 : (sel == 1 ? bnr1 : bnr2);
        void* Out_ = sel == 0 ? O0_ : (sel == 1 ? O1_ : O2_);
        double p[4] = {0.0, 0.0, 0.0, 0.0};
        for (int k = lane; k < CIN; k += 64) {
            const double w = (double)Wx[(size_t)o * CIN + k];
#pragma unroll
            for (int t = 0; t < 4; ++t) {
                size_t xi;
                if constexpr (XE_FM)
                    xi = (((size_t)(t * BB + b) * (NN / 16) + (n >> 4)) * (CIN / 32)
                          + (k >> 5)) * 512 + ((k >> 3) & 3) * 128 + (n & 15) * 8 + (k & 7);
                else
                    xi = ((size_t)(t * BB + b) * CIN + k) * NN + n;
                double xv;
                if constexpr (XE_BF16) xv = (double)bf16f(((const u16*)Xe_)[xi]);
                else                   xv = (double)((const float*)Xe_)[xi];
                p[t] += w * xv;
            }
        }
#pragma unroll
        for (int off = 32; off; off >>= 1)
#pragma unroll
            for (int t = 0; t < 4; ++t) p[t] += __shfl_down(p[t], off);
        if (lane == 0) {
            const double scale = bnd[(OUT_MODE == 0 ? sel * 256 : 0) + o];
            const double be = (double)bnr[1 * O + o];
            const double mu = (double)bnr[2 * O + o];
            double bi = 0.0;
            if constexpr (OUT_MODE != 0) bi = (double)bias[o];
            double v = 0.0;
#pragma unroll
            for (int t = 0; t < TT; ++t) {
                const double val = (p[t] + bi - mu) * scale + be;
                v = v + (val - v) * 0.5;
                const double sd = (v >= 1.0) ? 1.0 : 0.0;
                if constexpr (OUT_MODE == 2) {
                    const size_t fm = (((size_t)(t * BB + b) * (NN / 16) + (n >> 4))
                                       * (O / 32) + (o >> 5)) * 512
                                    + ((o >> 3) & 3) * 128 + (n & 15) * 8 + (o & 7);
                    ((u16*)Out_)[fm] = (sd > 0.5) ? (u16)0x3F80 : (u16)0;
                } else {
                    const size_t idx = (((size_t)t * BB + b) * O + o) * NN + n;
                    if constexpr (OUT_MODE == 0)
                        ((u16*)Out_)[idx] = (sd > 0.5) ? (u16)0x3F80 : (u16)0;
                    else
                        ((float*)Out_)[idx] = (float)((double)base[idx] + sd);
                }
                v = v * (1.0 - sd);
            }
        }
    }
}

// ---- kv via MFMA: one wave per (t,b,h); exact 0/1 bf16 spikes ----
__global__ __launch_bounds__(256) void kv_mfma(
    const u16* __restrict__ k_s, const u16* __restrict__ v_s,
    float* __restrict__ kv)
{
    const int lane = threadIdx.x & 63;
    const int wave = threadIdx.x >> 6;
    const int unit = blockIdx.x * 4 + wave;   // (t*BB+b)*HEADS + h
    const int h = unit & 7;
    const int m = unit >> 3;
    const int lr = lane & 15, lk = lane >> 4;
    const size_t base = ((size_t)m * CC + h * DD) * NN;

    f32x4 acc[2][2];
#pragma unroll
    for (int mt = 0; mt < 2; ++mt)
#pragma unroll
        for (int nt = 0; nt < 2; ++nt)
            acc[mt][nt] = (f32x4){0.f, 0.f, 0.f, 0.f};

#pragma unroll 4
    for (int ks = 0; ks < 32; ++ks) {
        s16x8 a[2], bf[2];
#pragma unroll
        for (int mt = 0; mt < 2; ++mt)
            a[mt] = *(const s16x8*)&k_s[base + (size_t)(mt * 16 + lr) * NN
                                         + ks * 32 + lk * 8];
#pragma unroll
        for (int nt = 0; nt < 2; ++nt)
            bf[nt] = *(const s16x8*)&v_s[base + (size_t)(nt * 16 + lr) * NN
                                          + ks * 32 + lk * 8];
#pragma unroll
        for (int mt = 0; mt < 2; ++mt)
#pragma unroll
            for (int nt = 0; nt < 2; ++nt)
                acc[mt][nt] = __builtin_amdgcn_mfma_f32_16x16x32_bf16(
                    a[mt], bf[nt], acc[mt][nt], 0, 0, 0);
    }
#pragma unroll
    for (int mt = 0; mt < 2; ++mt)
#pragma unroll
        for (int nt = 0; nt < 2; ++nt)
#pragma unroll
            for (int r = 0; r < 4; ++r)
                kv[(size_t)unit * 1024 + (mt * 16 + lk * 4 + r) * 32
                   + nt * 16 + lr] = acc[mt][nt][r];
}

// a = 0.125 * q @ kv -> LIF(0.5); bf16 q spikes (exact); bf16 spike out [c][n]
__global__ __launch_bounds__(256) void attn_a_lif(
    const u16* __restrict__ q_s, const float* __restrict__ kv,
    u16* __restrict__ a_s)
{
    const int tid = threadIdx.x;
    const int n = blockIdx.x * 256 + tid;
    const int c = blockIdx.y;
    const int b = blockIdx.z;
    const int h = c >> 5;
    const int e = c & 31;
    __shared__ float kvs[TT][32];
    if (tid < 128) {
        int t = tid >> 5, d2 = tid & 31;
        kvs[t][d2] = kv[(((size_t)t * BB + b) * HEADS + h) * 1024 + d2 * 32 + e];
    }
    __syncthreads();
    float val[TT];
#pragma unroll
    for (int t = 0; t < TT; ++t) {
        float s = 0.f;
        const size_t qb = (((size_t)t * BB + b) * CC + h * DD) * NN + n;
#pragma unroll 8
        for (int d2 = 0; d2 < 32; ++d2)
            s += bf16f(q_s[qb + (size_t)d2 * NN]) * kvs[t][d2];
        val[t] = s * 0.125f;
    }
    float v = 0.f;
#pragma unroll
    for (int t = 0; t < TT; ++t) {
        v = v + (val[t] - v) * 0.5f;
        float s = (v >= 0.5f) ? 1.f : 0.f;
        a_s[(((size_t)t * BB + b) * CC + c) * NN + n] = (s > 0.5f) ? (u16)0x3F80 : (u16)0;
        v = v * (1.f - s);
    }
}

extern "C" void kernel_launch(void* const* d_in, const int* in_sizes, int n_in,
                              void* d_out, int out_size, void* d_ws, size_t ws_size,
                              hipStream_t stream)
{
    const float* x       = (const float*)d_in[0];
    const float* q_w     = (const float*)d_in[1];
    const float* q_bn    = (const float*)d_in[2];
    const float* k_w     = (const float*)d_in[3];
    const float* k_bn    = (const float*)d_in[4];
    const float* v_w     = (const float*)d_in[5];
    const float* v_bn    = (const float*)d_in[6];
    const float* proj_w  = (const float*)d_in[7];
    const float* proj_b  = (const float*)d_in[8];
    const float* proj_bn = (const float*)d_in[9];
    const float* mlp1_w  = (const float*)d_in[10];
    const float* mlp1_b  = (const float*)d_in[11];
    const float* mlp1_bn = (const float*)d_in[12];
    const float* mlp2_w  = (const float*)d_in[13];
    const float* mlp2_b  = (const float*)d_in[14];
    const float* mlp2_bn = (const float*)d_in[15];

    const size_t SZ = (size_t)TT * BB * CC * NN;   // 8388608
    const size_t U = SZ * 2;                       // 16.75 MB unit
    char* ws = (char*)d_ws;
    u16*   xTh  = (u16*)(ws);              // FM x planes; dead after qkv
    u16*   xTl  = (u16*)(ws + U);
    u16*   q_s  = (u16*)(ws + 2*U);        // natural [c][n]
    u16*   k_s  = (u16*)(ws + 3*U);
    u16*   v_s  = (u16*)(ws + 4*U);
    u16*   a_s  = (u16*)(ws);              // overlays xTh (attn out, natural)
    u16*   aT   = (u16*)(ws + U);          // overlays xTl (FM of a_s)
    float* x_new= (float*)(ws + 2*U);      // overlays q_s,k_s (natural f32)
    u16*   xnTh = (u16*)(ws + 4*U);        // overlays v_s (FM planes)
    u16*   xnTl = (u16*)(ws + 5*U);
    u16*   h1T  = (u16*)(ws + 10*U);       // FM spikes (written directly)
    char* wp = ws + 14*U;
    float* kvb = (float*)wp; wp += (size_t)262144 * 4;
    u16* qh  = (u16*)wp; wp += 65536 * 2;  u16* ql  = (u16*)wp; wp += 65536 * 2;
    u16* kh  = (u16*)wp; wp += 65536 * 2;  u16* kl  = (u16*)wp; wp += 65536 * 2;
    u16* vh  = (u16*)wp; wp += 65536 * 2;  u16* vl  = (u16*)wp; wp += 65536 * 2;
    u16* ph  = (u16*)wp; wp += 65536 * 2;  u16* pl  = (u16*)wp; wp += 65536 * 2;
    u16* m1h = (u16*)wp; wp += 262144 * 2; u16* m1l = (u16*)wp; wp += 262144 * 2;
    u16* m2h = (u16*)wp; wp += 262144 * 2; u16* m2l = (u16*)wp; wp += 262144 * 2;
    float2* bnf = (float2*)wp; wp += 2304 * 8;
    double* bnd = (double*)wp; wp += 2304 * 8;
    u32* cnts = (u32*)wp; wp += 4 * 4;
    u32* list0 = (u32*)wp; wp += FIXCAP * 4;
    u32* list1 = (u32*)wp; wp += FIXCAP * 4;
    u32* list2 = (u32*)wp; wp += FIXCAP * 4;
    u32* list3 = (u32*)wp;

    dim3 blk(256);

    zero_counters<<<dim3(1), dim3(64), 0, stream>>>(cnts);

    // prep: weights -> FM hi/lo; x -> FM hi/lo; BN constants
    prep_split_fm<256, 256>  <<<dim3(32),  blk, 0, stream>>>(q_w,    qh,  ql);
    prep_split_fm<256, 256>  <<<dim3(32),  blk, 0, stream>>>(k_w,    kh,  kl);
    prep_split_fm<256, 256>  <<<dim3(32),  blk, 0, stream>>>(v_w,    vh,  vl);
    prep_split_fm<256, 256>  <<<dim3(32),  blk, 0, stream>>>(proj_w, ph,  pl);
    prep_split_fm<1024, 256> <<<dim3(128), blk, 0, stream>>>(mlp1_w, m1h, m1l);
    prep_split_fm<256, 1024> <<<dim3(128), blk, 0, stream>>>(mlp2_w, m2h, m2l);
    trans_split_fm<256, 1024><<<dim3(16, 4, 32), blk, 0, stream>>>(x, xTh, xTl);
    prep_bn<<<dim3(9), blk, 0, stream>>>(q_bn, k_bn, v_bn, proj_bn, mlp1_bn,
                                         mlp2_bn, proj_b, mlp1_b, mlp2_b, bnf, bnd);

    // qkv: FM x -> bf16 spike trains [c][n]
    conv_kernel<true, 256, 0, true, 256><<<dim3(12, 16, 8), blk, 0, stream>>>(
        xTh, xTl, qh, ql, kh, kl, vh, vl, bnf, q_s, k_s, v_s, nullptr,
        cnts + 0, list0);
    fixup_kernel<false, false, 256, 0, 256><<<dim3(1024), dim3(64), 0, stream>>>(
        cnts + 0, list0, x, q_w, k_w, v_w, q_bn, k_bn, v_bn, nullptr, bnd,
        q_s, k_s, v_s, nullptr);

    // attention (exact): kv via MFMA, then a + LIF, then FM transpose of a
    kv_mfma<<<dim3(64), blk, 0, stream>>>(k_s, v_s, kvb);
    attn_a_lif<<<dim3(4, 256, 8), blk, 0, stream>>>(q_s, kvb, a_s);
    trans_u16_fm<256, 1024><<<dim3(16, 4, 32), blk, 0, stream>>>(a_s, aT);

    // proj: FM a (exact bf16 B, 2-MFMA) -> x_new f32 [c][n] (+x base)
    conv_kernel<false, 256, 1, false, 256><<<dim3(4, 16, 8), blk, 0, stream>>>(
        aT, nullptr, ph, pl, nullptr, nullptr, nullptr, nullptr,
        bnf + 768, x_new, nullptr, nullptr, x, cnts + 1, list1);
    fixup_kernel<true, false, 256, 1, 256><<<dim3(1024), dim3(64), 0, stream>>>(
        cnts + 1, list1, a_s, proj_w, nullptr, nullptr, proj_bn, nullptr,
        nullptr, proj_b, bnd + 768, x_new, nullptr, nullptr, x);

    // transpose+split x_new -> FM planes (after fixup!)
    trans_split_fm<256, 1024><<<dim3(16, 4, 32), blk, 0, stream>>>(x_new, xnTh, xnTl);

    // mlp1: FM x_new -> h1T FM spikes DIRECTLY
    conv_kernel<true, 256, 2, false, 1024><<<dim3(16, 16, 8), blk, 0, stream>>>(
        xnTh, xnTl, m1h, m1l, nullptr, nullptr, nullptr, nullptr,
        bnf + 1024, h1T, nullptr, nullptr, nullptr, cnts + 2, list2);
    fixup_kernel<false, false, 256, 2, 1024><<<dim3(1024), dim3(64), 0, stream>>>(
        cnts + 2, list2, x_new, mlp1_w, nullptr, nullptr, mlp1_bn, nullptr,
        nullptr, mlp1_b, bnd + 1024, h1T, nullptr, nullptr, nullptr);

    // mlp2: FM h1 (exact bf16 B, 2-MFMA) -> d_out (+x_new base)
    conv_kernel<false, 1024, 3, false, 256><<<dim3(4, 16, 8), blk, 0, stream>>>(
        h1T, nullptr, m2h, m2l, nullptr, nullptr, nullptr, nullptr,
        bnf + 2048, d_out, nullptr, nullptr, x_new, cnts + 3, list3);
    fixup_kernel<true, true, 1024, 3, 256><<<dim3(1024), dim3(64), 0, stream>>>(
        cnts + 3, list3, h1T, mlp2_w, nullptr, nullptr, mlp2_bn, nullptr,
        nullptr, mlp2_b, bnd + 2048, d_out, nullptr, nullptr, x_new);
}

// Round 22
// 376.878 us; speedup vs baseline: 1.1547x; 1.1547x over previous
//
#include <hip/hip_runtime.h>
#include <cstdint>
#include <cstddef>

#define TT 4
#define BB 8
#define CC 256
#define NN 1024
#define HEADS 8
#define DD 32
#define FIXCAP 262144u

typedef __attribute__((ext_vector_type(4))) float f32x4;
typedef __attribute__((ext_vector_type(8))) short s16x8;
typedef unsigned short u16;
typedef unsigned int   u32;

__device__ __forceinline__ u16 bf16_rne(float x) {
    u32 u = __float_as_uint(x);
    return (u16)((u + 0x7FFFu + ((u >> 16) & 1u)) >> 16);
}
__device__ __forceinline__ float bf16f(u16 h) {
    return __uint_as_float(((u32)h) << 16);
}

__global__ __launch_bounds__(64) void zero_counters(u32* c) {
    if (threadIdx.x < 4) c[threadIdx.x] = 0;
}

// Fragment-major index for a [R][K] bf16 plane:
//   FM(r,k) = ((r>>4)*(K/32) + (k>>5))*512 + ((k>>3)&3)*128 + (r&15)*8 + (k&7)

// ---- prep: weights f32 [O][K] -> FM hi/lo bf16 planes ----
template<int OO, int CIN>
__global__ __launch_bounds__(256) void prep_split_fm(
    const float* __restrict__ src, u16* __restrict__ h, u16* __restrict__ l)
{
    const int id = blockIdx.x * 256 + threadIdx.x;
    if (id >= OO * CIN / 8) return;
    const int o = id / (CIN / 8), kq = id % (CIN / 8);
    const float* p = src + (size_t)o * CIN + kq * 8;
    s16x8 hh, ll;
#pragma unroll
    for (int e = 0; e < 8; ++e) {
        float f = p[e];
        u16 hb = bf16_rne(f);
        hh[e] = (short)hb;
        ll[e] = (short)bf16_rne(f - bf16f(hb));
    }
    const int lane = (kq & 3) * 16 + (o & 15);
    const size_t dst = (((size_t)(o >> 4) * (CIN / 32) + (kq >> 2)) * 64 + lane) * 8;
    *(s16x8*)&h[dst] = hh;
    *(s16x8*)&l[dst] = ll;
}

// ---- transpose+split: f32 [m][K][N] -> FM hi/lo planes over [N rows][K cols] ----
template<int K, int N>
__global__ __launch_bounds__(256) void trans_split_fm(
    const float* __restrict__ src, u16* __restrict__ dh, u16* __restrict__ dl)
{
    __shared__ float tile[64][65];
    const int tid = threadIdx.x;
    const int n0 = blockIdx.x * 64, k0 = blockIdx.y * 64, m = blockIdx.z;
    for (int i = tid; i < 4096; i += 256) {
        int kk = i >> 6, nn = i & 63;
        tile[kk][nn] = src[((size_t)m * K + k0 + kk) * N + n0 + nn];
    }
    __syncthreads();
    const size_t plane = (size_t)m * (N / 16) * (K / 32) * 512;
    for (int it = tid; it < 512; it += 256) {
        const int nn = it >> 3, kq = it & 7;
        s16x8 hh, ll;
#pragma unroll
        for (int e = 0; e < 8; ++e) {
            float f = tile[kq * 8 + e][nn];
            u16 hb = bf16_rne(f);
            hh[e] = (short)hb;
            ll[e] = (short)bf16_rne(f - bf16f(hb));
        }
        const int n = n0 + nn;
        const int ks = (k0 >> 5) + (kq >> 2), lk = kq & 3;
        const size_t dst = plane + (((size_t)(n >> 4) * (K / 32) + ks) * 64
                                    + lk * 16 + (n & 15)) * 8;
        *(s16x8*)&dh[dst] = hh;
        *(s16x8*)&dl[dst] = ll;
    }
}

// ---- transpose bf16 [m][K][N] -> FM plane over [N rows][K cols] ----
template<int K, int N>
__global__ __launch_bounds__(256) void trans_u16_fm(
    const u16* __restrict__ src, u16* __restrict__ dst)
{
    __shared__ u16 tile[64][72];
    const int tid = threadIdx.x;
    const int n0 = blockIdx.x * 64, k0 = blockIdx.y * 64, m = blockIdx.z;
    for (int i = tid; i < 4096; i += 256) {
        int kk = i >> 6, nn = i & 63;
        tile[kk][nn] = src[((size_t)m * K + k0 + kk) * N + n0 + nn];
    }
    __syncthreads();
    const size_t plane = (size_t)m * (N / 16) * (K / 32) * 512;
    for (int it = tid; it < 512; it += 256) {
        const int nn = it >> 3, kq = it & 7;
        s16x8 hh;
#pragma unroll
        for (int e = 0; e < 8; ++e) hh[e] = (short)tile[kq * 8 + e][nn];
        const int n = n0 + nn;
        const int ks = (k0 >> 5) + (kq >> 2), lk = kq & 3;
        const size_t d = plane + (((size_t)(n >> 4) * (K / 32) + ks) * 64
                                  + lk * 16 + (n & 15)) * 8;
        *(s16x8*)&dst[d] = hh;
    }
}

// ---- per-channel BN constants ----
__global__ __launch_bounds__(256) void prep_bn(
    const float* qbn, const float* kbn, const float* vbn, const float* pbn,
    const float* m1bn, const float* m2bn,
    const float* pb, const float* m1b, const float* m2b,
    float2* __restrict__ bnf, double* __restrict__ bnd)
{
    int c = blockIdx.x * 256 + threadIdx.x;
    if (c >= 2304) return;
    const float* bn; int ch, O; double bi = 0.0;
    if (c < 1024) {
        int s = c >> 8; ch = c & 255; O = 256;
        bn = s == 0 ? qbn : s == 1 ? kbn : s == 2 ? vbn : pbn;
        if (s == 3) bi = (double)pb[ch];
    } else if (c < 2048) { ch = c - 1024; O = 1024; bn = m1bn; bi = (double)m1b[ch]; }
    else                 { ch = c - 2048; O = 256;  bn = m2bn; bi = (double)m2b[ch]; }
    double g = (double)bn[0*O+ch], be = (double)bn[1*O+ch];
    double mu = (double)bn[2*O+ch], var = (double)bn[3*O+ch];
    double sd = g / sqrt(var + 1e-5);
    bnf[c] = make_float2((float)sd, (float)((bi - mu) * sd + be));
    bnd[c] = sd;
}

// ---- conv1x1 + BN + LIF: fragment-major direct-global bf16-split MFMA ----
// ROUND-20 PROVEN CONFIG: 2-deep full double-buffer (A+B), launch_bounds(256,2)
// (VGPR 108, no spill). OUT_MODE: 0 bf16 spikes [c][n] | 1 f32 +base |
// 2 bf16 spikes FM-DIRECT | 3 f32 +base.
template<bool SPLIT_IN, int CIN, int OUT_MODE, bool TRIPLE, int O>
__global__ __launch_bounds__(256, 2) void conv_kernel(
    const u16* __restrict__ XTH, const u16* __restrict__ XTL,
    const u16* __restrict__ WH0, const u16* __restrict__ WL0,
    const u16* __restrict__ WH1, const u16* __restrict__ WL1,
    const u16* __restrict__ WH2, const u16* __restrict__ WL2,
    const float2* __restrict__ bnf,
    void* __restrict__ O0_, void* __restrict__ O1_, void* __restrict__ O2_,
    const float* __restrict__ base,
    u32* __restrict__ cnt, u32* __restrict__ list)
{
    constexpr float EPS = 3e-4f;
    constexpr u32 OT = TRIPLE ? 12 : O / 64;
    constexpr u32 NWG = OT * 16 * 8;
    constexpr int NS = CIN / 32;
    constexpr u32 KS = (u32)(CIN / 32);
    __shared__ float pre[2 * 64 * 64];

    const int tid  = threadIdx.x;
    const int lane = tid & 63;
    const int wave = tid >> 6;          // == timestep t
    const int lr   = lane & 15;
    const int lk   = lane >> 4;

    const u32 orig = blockIdx.x + OT * (blockIdx.y + 16u * blockIdx.z);
    const u32 flat = (orig & 7u) * (NWG >> 3) + (orig >> 3);
    const u32 otile = flat % OT;
    const u32 rem   = flat / OT;
    const int n0 = (int)(rem & 15u) * 64;
    const int b  = (int)(rem >> 4);

    int o0, sel;
    const u16 *WH, *WL;
    void* Out_;
    if constexpr (TRIPLE) {
        sel = (int)(otile >> 2);
        o0 = (int)(otile & 3) * 64;
        WH = sel==0?WH0:sel==1?WH1:WH2;  WL = sel==0?WL0:sel==1?WL1:WL2;
        Out_ = sel==0?O0_:sel==1?O1_:O2_;
    } else {
        sel = 0; o0 = (int)otile * 64; WH = WH0; WL = WL0; Out_ = O0_;
    }
    const int cofs = sel * 256;

    f32x4 acc[4][4];
#pragma unroll
    for (int mf = 0; mf < 4; ++mf)
#pragma unroll
        for (int nf = 0; nf < 4; ++nf)
            acc[mf][nf] = (f32x4){0.f, 0.f, 0.f, 0.f};

    u32 afm[4], bfm[4];
#pragma unroll
    for (int mf = 0; mf < 4; ++mf)
        afm[mf] = ((u32)(o0 / 16 + mf) * KS) * 512u + (u32)lane * 8u;
    const u32 xplane = (u32)(wave * BB + b) * (u32)(NN / 16) * KS * 512u;
#pragma unroll
    for (int nf = 0; nf < 4; ++nf)
        bfm[nf] = xplane + ((u32)(n0 / 16 + nf) * KS) * 512u + (u32)lane * 8u;

    struct Frag { s16x8 aH[4], aL[4], bH[4], bL[4]; };
    Frag f0, f1;

    auto loadstep = [&](int ks, Frag& f) {
        const u32 ko = (u32)ks * 512u;
#pragma unroll
        for (int mf = 0; mf < 4; ++mf) {
            f.aH[mf] = *(const s16x8*)&WH[(size_t)(afm[mf] + ko)];
            f.aL[mf] = *(const s16x8*)&WL[(size_t)(afm[mf] + ko)];
        }
#pragma unroll
        for (int nf = 0; nf < 4; ++nf) {
            f.bH[nf] = *(const s16x8*)&XTH[(size_t)(bfm[nf] + ko)];
            if constexpr (SPLIT_IN)
                f.bL[nf] = *(const s16x8*)&XTL[(size_t)(bfm[nf] + ko)];
        }
    };
    auto compute = [&](Frag& f) {
        __builtin_amdgcn_s_setprio(1);
#pragma unroll
        for (int mf = 0; mf < 4; ++mf)
#pragma unroll
            for (int nf = 0; nf < 4; ++nf) {
                acc[mf][nf] = __builtin_amdgcn_mfma_f32_16x16x32_bf16(
                    f.aH[mf], f.bH[nf], acc[mf][nf], 0, 0, 0);
                acc[mf][nf] = __builtin_amdgcn_mfma_f32_16x16x32_bf16(
                    f.aL[mf], f.bH[nf], acc[mf][nf], 0, 0, 0);
                if constexpr (SPLIT_IN)
                    acc[mf][nf] = __builtin_amdgcn_mfma_f32_16x16x32_bf16(
                        f.aH[mf], f.bL[nf], acc[mf][nf], 0, 0, 0);
            }
        __builtin_amdgcn_s_setprio(0);
    };

    loadstep(0, f0);
#pragma unroll
    for (int ks = 0; ks < NS; ++ks) {
        if ((ks & 1) == 0) {
            if (ks + 1 < NS) loadstep(ks + 1, f1);
            compute(f0);
        } else {
            if (ks + 1 < NS) loadstep(ks + 1, f0);
            compute(f1);
        }
    }

    const int nl = tid & 63;
    const int og = wave;

    auto dump = [&](int slot) {
#pragma unroll
        for (int mf = 0; mf < 4; ++mf)
#pragma unroll
            for (int nf = 0; nf < 4; ++nf)
#pragma unroll
                for (int r = 0; r < 4; ++r)
                    pre[(size_t)(slot * 64 + mf * 16 + lk * 4 + r) * 64
                        + nf * 16 + lr] = acc[mf][nf][r];
    };

    float2 sc[16];
#pragma unroll
    for (int i = 0; i < 16; ++i) sc[i] = bnf[cofs + o0 + og * 16 + i];

    unsigned flags = 0;
    float vst[16];
    u32 spA = 0, spB = 0;   // OUT_MODE 2: spike bits (t0/t1 in A, t2/t3 in B)

    auto do_round = [&](int tbase) {
#pragma unroll
        for (int i = 0; i < 16; ++i) {
            const int o = o0 + og * 16 + i;
            float v = (tbase == 0) ? 0.f : vst[i];
#pragma unroll
            for (int dt = 0; dt < 2; ++dt) {
                const int t = tbase + dt;
                float val = fmaf(pre[(size_t)(dt * 64 + og * 16 + i) * 64 + nl], sc[i].x, sc[i].y);
                v = v + (val - v) * 0.5f;
                if (fabsf(v - 1.0f) < EPS) flags |= (1u << i);
                float s = (v >= 1.0f) ? 1.f : 0.f;
                if constexpr (OUT_MODE == 2) {
                    const u32 bit = (s > 0.5f) ? 1u : 0u;
                    if (tbase == 0) spA |= bit << (dt * 16 + i);
                    else            spB |= bit << (dt * 16 + i);
                } else {
                    const size_t idx = (((size_t)t * BB + b) * O + o) * NN + n0 + nl;
                    if constexpr (OUT_MODE == 0)
                        ((u16*)Out_)[idx] = (s > 0.5f) ? (u16)0x3F80 : (u16)0;
                    else
                        ((float*)Out_)[idx] = base[idx] + s;
                }
                v *= (1.f - s);
            }
            vst[i] = v;
        }
    };

    __syncthreads();
    if (wave < 2) dump(wave);
    __syncthreads();
    do_round(0);
    __syncthreads();
    if (wave >= 2) dump(wave - 2);
    __syncthreads();
    do_round(2);

    if constexpr (OUT_MODE == 2) {
        __syncthreads();
        u16* lds16 = (u16*)pre;
#pragma unroll
        for (int dt = 0; dt < 2; ++dt)
#pragma unroll
            for (int i = 0; i < 16; ++i) {
                const int ol = og * 16 + i;
                const int loc = ((nl >> 4) * 2 + (ol >> 5)) * 512
                              + ((ol >> 3) & 3) * 128 + (nl & 15) * 8 + (ol & 7);
                lds16[dt * 4096 + loc] =
                    ((spA >> (dt * 16 + i)) & 1u) ? (u16)0x3F80 : (u16)0;
                lds16[(2 + dt) * 4096 + loc] =
                    ((spB >> (dt * 16 + i)) & 1u) ? (u16)0x3F80 : (u16)0;
            }
        __syncthreads();
        constexpr u32 KO = (u32)(O / 32);
        for (int idx2 = tid; idx2 < 2048; idx2 += 256) {
            const int t = idx2 >> 9, rem2 = idx2 & 511;
            const int c = rem2 >> 6, pos = (rem2 & 63) * 8;
            const int nt = c >> 1, ob = c & 1;
            const size_t gb = (((size_t)(t * BB + b) * (NN / 16) + (n0 / 16 + nt)) * KO
                               + (o0 / 32 + ob)) * 512 + pos;
            *(s16x8*)&((u16*)Out_)[gb] = *(const s16x8*)&lds16[t * 4096 + c * 512 + pos];
        }
    }

    if (flags) {
#pragma unroll 1
        for (int i = 0; i < 16; ++i) {
            if (!(flags & (1u << i))) continue;
            const int o = o0 + og * 16 + i;
            const u32 ent = ((u32)sel << 23) | ((u32)b << 20) | ((u32)o << 10)
                          | (u32)(n0 + nl);
            const u32 idx = atomicAdd(cnt, 1u);
            if (idx < FIXCAP) list[idx] = ent;
        }
    }
}

// ---- exact f64 fixup: one wave per flagged column, lane-parallel K ----
template<bool XE_BF16, bool XE_FM, int CIN, int OUT_MODE, int O>
__global__ __launch_bounds__(64) void fixup_kernel(
    const u32* __restrict__ cnt, const u32* __restrict__ list,
    const void* __restrict__ Xe_,
    const float* __restrict__ Wx0, const float* __restrict__ Wx1,
    const float* __restrict__ Wx2,
    const float* __restrict__ bnr0, const float* __restrict__ bnr1,
    const float* __restrict__ bnr2, const float* __restrict__ bias,
    const double* __restrict__ bnd,
    void* __restrict__ O0_, void* __restrict__ O1_, void* __restrict__ O2_,
    const float* __restrict__ base)
{
    const u32 c0 = *cnt;
    const u32 count = c0 > FIXCAP ? FIXCAP : c0;
    const int lane = threadIdx.x;
    for (u32 e = blockIdx.x; e < count; e += gridDim.x) {
        const u32 ent = list[e];
        const int n = (int)(ent & 1023u);
        const int o = (int)((ent >> 10) & 1023u);
        const int b = (int)((ent >> 20) & 7u);
        const int sel = (int)(ent >> 23);
        const float* Wx  = sel == 0 ? Wx0  : (sel == 1 ? Wx1  : Wx2);
        const float* bnr = sel == 0 ? bnr0 : (sel == 1 ? bnr1 : bnr2);
        void* Out_ = sel == 0 ? O0_ : (sel == 1 ? O1_ : O2_);
        double p[4] = {0.0, 0.0, 0.0, 0.0};
        for (int k = lane; k < CIN; k += 64) {
            const double w = (double)Wx[(size_t)o * CIN + k];
#pragma unroll
            for (int t = 0; t < 4; ++t) {
                size_t xi;
                if constexpr (XE_FM)
                    xi = (((size_t)(t * BB + b) * (NN / 16) + (n >> 4)) * (CIN / 32)
                          + (k >> 5)) * 512 + ((k >> 3) & 3) * 128 + (n & 15) * 8 + (k & 7);
                else
                    xi = ((size_t)(t * BB + b) * CIN + k) * NN + n;
                double xv;
                if constexpr (XE_BF16) xv = (double)bf16f(((const u16*)Xe_)[xi]);
                else                   xv = (double)((const float*)Xe_)[xi];
                p[t] += w * xv;
            }
        }
#pragma unroll
        for (int off = 32; off; off >>= 1)
#pragma unroll
            for (int t = 0; t < 4; ++t) p[t] += __shfl_down(p[t], off);
        if (lane == 0) {
            const double scale = bnd[(OUT_MODE == 0 ? sel * 256 : 0) + o];
            const double be = (double)bnr[1 * O + o];
            const double mu = (double)bnr[2 * O + o];
            double bi = 0.0;
            if constexpr (OUT_MODE != 0) bi = (double)bias[o];
            double v = 0.0;
#pragma unroll
            for (int t = 0; t < TT; ++t) {
                const double val = (p[t] + bi - mu) * scale + be;
                v = v + (val - v) * 0.5;
                const double sd = (v >= 1.0) ? 1.0 : 0.0;
                if constexpr (OUT_MODE == 2) {
                    const size_t fm = (((size_t)(t * BB + b) * (NN / 16) + (n >> 4))
                                       * (O / 32) + (o >> 5)) * 512
                                    + ((o >> 3) & 3) * 128 + (n & 15) * 8 + (o & 7);
                    ((u16*)Out_)[fm] = (sd > 0.5) ? (u16)0x3F80 : (u16)0;
                } else {
                    const size_t idx = (((size_t)t * BB + b) * O + o) * NN + n;
                    if constexpr (OUT_MODE == 0)
                        ((u16*)Out_)[idx] = (sd > 0.5) ? (u16)0x3F80 : (u16)0;
                    else
                        ((float*)Out_)[idx] = (float)((double)base[idx] + sd);
                }
                v = v * (1.0 - sd);
            }
        }
    }
}

// ---- kv via MFMA: one wave per (t,b,h); exact 0/1 bf16 spikes ----
__global__ __launch_bounds__(256) void kv_mfma(
    const u16* __restrict__ k_s, const u16* __restrict__ v_s,
    float* __restrict__ kv)
{
    const int lane = threadIdx.x & 63;
    const int wave = threadIdx.x >> 6;
    const int unit = blockIdx.x * 4 + wave;   // (t*BB+b)*HEADS + h
    const int h = unit & 7;
    const int m = unit >> 3;
    const int lr = lane & 15, lk = lane >> 4;
    const size_t base = ((size_t)m * CC + h * DD) * NN;

    f32x4 acc[2][2];
#pragma unroll
    for (int mt = 0; mt < 2; ++mt)
#pragma unroll
        for (int nt = 0; nt < 2; ++nt)
            acc[mt][nt] = (f32x4){0.f, 0.f, 0.f, 0.f};

#pragma unroll 4
    for (int ks = 0; ks < 32; ++ks) {
        s16x8 a[2], bf[2];
#pragma unroll
        for (int mt = 0; mt < 2; ++mt)
            a[mt] = *(const s16x8*)&k_s[base + (size_t)(mt * 16 + lr) * NN
                                         + ks * 32 + lk * 8];
#pragma unroll
        for (int nt = 0; nt < 2; ++nt)
            bf[nt] = *(const s16x8*)&v_s[base + (size_t)(nt * 16 + lr) * NN
                                          + ks * 32 + lk * 8];
#pragma unroll
        for (int mt = 0; mt < 2; ++mt)
#pragma unroll
            for (int nt = 0; nt < 2; ++nt)
                acc[mt][nt] = __builtin_amdgcn_mfma_f32_16x16x32_bf16(
                    a[mt], bf[nt], acc[mt][nt], 0, 0, 0);
    }
#pragma unroll
    for (int mt = 0; mt < 2; ++mt)
#pragma unroll
        for (int nt = 0; nt < 2; ++nt)
#pragma unroll
            for (int r = 0; r < 4; ++r)
                kv[(size_t)unit * 1024 + (mt * 16 + lk * 4 + r) * 32
                   + nt * 16 + lr] = acc[mt][nt][r];
}

// a = 0.125 * q @ kv -> LIF(0.5); LDS-staged q tile (coalesced reads).
// Block: 64 n x 32 e (one h) x 1 b; 256 threads = (64 n, 4 e-groups).
__global__ __launch_bounds__(256) void attn_a_lif(
    const u16* __restrict__ q_s, const float* __restrict__ kv,
    u16* __restrict__ a_s)
{
    __shared__ u16 qt[TT][32][64];       // q spikes [t][d][n-tile] 16 KB
    __shared__ float kvs[TT][32][32];    // kv [t][d][e] 16 KB
    const int tid = threadIdx.x;
    const int n0 = blockIdx.x * 64;
    const int h  = blockIdx.y;
    const int b  = blockIdx.z;

    // stage q tile: 4t x 32d x 64n, coalesced 64-wide rows
    for (int i = tid; i < TT * 32 * 64 / 4; i += 256) {
        const int t = i >> 9, rem = i & 511;      // rem: d*16 + n4 (n4 = n/4)
        const int d = rem >> 4, n4 = rem & 15;
        const size_t g = (((size_t)t * BB + b) * CC + h * DD + d) * NN + n0 + n4 * 4;
        *(ushort4*)&qt[t][d][n4 * 4] = *(const ushort4*)&q_s[g];
    }
    // stage kv: 4t x 32d x 32e
    for (int i = tid; i < TT * 32 * 32 / 4; i += 256) {
        const int t = i >> 8, rem = i & 255;
        const int d = rem >> 3, e4 = rem & 7;
        const size_t g = (((size_t)t * BB + b) * HEADS + h) * 1024 + d * 32 + e4 * 4;
        *(float4*)&kvs[t][d][e4 * 4] = *(const float4*)&kv[g];
    }
    __syncthreads();

    const int nl = tid & 63;             // n within tile
    const int eg = tid >> 6;             // e-group: e = eg*8 .. eg*8+7
#pragma unroll
    for (int ei = 0; ei < 8; ++ei) {
        const int e = eg * 8 + ei;
        float val[TT];
#pragma unroll
        for (int t = 0; t < TT; ++t) {
            float s = 0.f;
#pragma unroll 8
            for (int d = 0; d < 32; ++d)
                s += bf16f(qt[t][d][nl]) * kvs[t][d][e];
            val[t] = s * 0.125f;
        }
        float v = 0.f;
#pragma unroll
        for (int t = 0; t < TT; ++t) {
            v = v + (val[t] - v) * 0.5f;
            float s = (v >= 0.5f) ? 1.f : 0.f;
            a_s[(((size_t)t * BB + b) * CC + h * DD + e) * NN + n0 + nl] =
                (s > 0.5f) ? (u16)0x3F80 : (u16)0;
            v = v * (1.f - s);
        }
    }
}

extern "C" void kernel_launch(void* const* d_in, const int* in_sizes, int n_in,
                              void* d_out, int out_size, void* d_ws, size_t ws_size,
                              hipStream_t stream)
{
    const float* x       = (const float*)d_in[0];
    const float* q_w     = (const float*)d_in[1];
    const float* q_bn    = (const float*)d_in[2];
    const float* k_w     = (const float*)d_in[3];
    const float* k_bn    = (const float*)d_in[4];
    const float* v_w     = (const float*)d_in[5];
    const float* v_bn    = (const float*)d_in[6];
    const float* proj_w  = (const float*)d_in[7];
    const float* proj_b  = (const float*)d_in[8];
    const float* proj_bn = (const float*)d_in[9];
    const float* mlp1_w  = (const float*)d_in[10];
    const float* mlp1_b  = (const float*)d_in[11];
    const float* mlp1_bn = (const float*)d_in[12];
    const float* mlp2_w  = (const float*)d_in[13];
    const float* mlp2_b  = (const float*)d_in[14];
    const float* mlp2_bn = (const float*)d_in[15];

    const size_t SZ = (size_t)TT * BB * CC * NN;   // 8388608
    const size_t U = SZ * 2;                       // 16.75 MB unit
    char* ws = (char*)d_ws;
    u16*   xTh  = (u16*)(ws);              // FM x planes; dead after qkv
    u16*   xTl  = (u16*)(ws + U);
    u16*   q_s  = (u16*)(ws + 2*U);        // natural [c][n]
    u16*   k_s  = (u16*)(ws + 3*U);
    u16*   v_s  = (u16*)(ws + 4*U);
    u16*   a_s  = (u16*)(ws);              // overlays xTh (attn out, natural)
    u16*   aT   = (u16*)(ws + U);          // overlays xTl (FM of a_s)
    float* x_new= (float*)(ws + 2*U);      // overlays q_s,k_s (natural f32)
    u16*   xnTh = (u16*)(ws + 4*U);        // overlays v_s (FM planes)
    u16*   xnTl = (u16*)(ws + 5*U);
    u16*   h1T  = (u16*)(ws + 10*U);       // FM spikes (written directly)
    char* wp = ws + 14*U;
    float* kvb = (float*)wp; wp += (size_t)262144 * 4;
    u16* qh  = (u16*)wp; wp += 65536 * 2;  u16* ql  = (u16*)wp; wp += 65536 * 2;
    u16* kh  = (u16*)wp; wp += 65536 * 2;  u16* kl  = (u16*)wp; wp += 65536 * 2;
    u16* vh  = (u16*)wp; wp += 65536 * 2;  u16* vl  = (u16*)wp; wp += 65536 * 2;
    u16* ph  = (u16*)wp; wp += 65536 * 2;  u16* pl  = (u16*)wp; wp += 65536 * 2;
    u16* m1h = (u16*)wp; wp += 262144 * 2; u16* m1l = (u16*)wp; wp += 262144 * 2;
    u16* m2h = (u16*)wp; wp += 262144 * 2; u16* m2l = (u16*)wp; wp += 262144 * 2;
    float2* bnf = (float2*)wp; wp += 2304 * 8;
    double* bnd = (double*)wp; wp += 2304 * 8;
    u32* cnts = (u32*)wp; wp += 4 * 4;
    u32* list0 = (u32*)wp; wp += FIXCAP * 4;
    u32* list1 = (u32*)wp; wp += FIXCAP * 4;
    u32* list2 = (u32*)wp; wp += FIXCAP * 4;
    u32* list3 = (u32*)wp;

    dim3 blk(256);

    zero_counters<<<dim3(1), dim3(64), 0, stream>>>(cnts);

    // prep: weights -> FM hi/lo; x -> FM hi/lo; BN constants
    prep_split_fm<256, 256>  <<<dim3(32),  blk, 0, stream>>>(q_w,    qh,  ql);
    prep_split_fm<256, 256>  <<<dim3(32),  blk, 0, stream>>>(k_w,    kh,  kl);
    prep_split_fm<256, 256>  <<<dim3(32),  blk, 0, stream>>>(v_w,    vh,  vl);
    prep_split_fm<256, 256>  <<<dim3(32),  blk, 0, stream>>>(proj_w, ph,  pl);
    prep_split_fm<1024, 256> <<<dim3(128), blk, 0, stream>>>(mlp1_w, m1h, m1l);
    prep_split_fm<256, 1024> <<<dim3(128), blk, 0, stream>>>(mlp2_w, m2h, m2l);
    trans_split_fm<256, 1024><<<dim3(16, 4, 32), blk, 0, stream>>>(x, xTh, xTl);
    prep_bn<<<dim3(9), blk, 0, stream>>>(q_bn, k_bn, v_bn, proj_bn, mlp1_bn,
                                         mlp2_bn, proj_b, mlp1_b, mlp2_b, bnf, bnd);

    // qkv: FM x -> bf16 spike trains [c][n]
    conv_kernel<true, 256, 0, true, 256><<<dim3(12, 16, 8), blk, 0, stream>>>(
        xTh, xTl, qh, ql, kh, kl, vh, vl, bnf, q_s, k_s, v_s, nullptr,
        cnts + 0, list0);
    fixup_kernel<false, false, 256, 0, 256><<<dim3(1024), dim3(64), 0, stream>>>(
        cnts + 0, list0, x, q_w, k_w, v_w, q_bn, k_bn, v_bn, nullptr, bnd,
        q_s, k_s, v_s, nullptr);

    // attention (exact): kv via MFMA, then a + LIF (LDS-staged), FM transpose
    kv_mfma<<<dim3(64), blk, 0, stream>>>(k_s, v_s, kvb);
    attn_a_lif<<<dim3(16, 8, 8), blk, 0, stream>>>(q_s, kvb, a_s);
    trans_u16_fm<256, 1024><<<dim3(16, 4, 32), blk, 0, stream>>>(a_s, aT);

    // proj: FM a (exact bf16 B, 2-MFMA) -> x_new f32 [c][n] (+x base)
    conv_kernel<false, 256, 1, false, 256><<<dim3(4, 16, 8), blk, 0, stream>>>(
        aT, nullptr, ph, pl, nullptr, nullptr, nullptr, nullptr,
        bnf + 768, x_new, nullptr, nullptr, x, cnts + 1, list1);
    fixup_kernel<true, false, 256, 1, 256><<<dim3(1024), dim3(64), 0, stream>>>(
        cnts + 1, list1, a_s, proj_w, nullptr, nullptr, proj_bn, nullptr,
        nullptr, proj_b, bnd + 768, x_new, nullptr, nullptr, x);

    // transpose+split x_new -> FM planes (after fixup!)
    trans_split_fm<256, 1024><<<dim3(16, 4, 32), blk, 0, stream>>>(x_new, xnTh, xnTl);

    // mlp1: FM x_new -> h1T FM spikes DIRECTLY
    conv_kernel<true, 256, 2, false, 1024><<<dim3(16, 16, 8), blk, 0, stream>>>(
        xnTh, xnTl, m1h, m1l, nullptr, nullptr, nullptr, nullptr,
        bnf + 1024, h1T, nullptr, nullptr, nullptr, cnts + 2, list2);
    fixup_kernel<false, false, 256, 2, 1024><<<dim3(1024), dim3(64), 0, stream>>>(
        cnts + 2, list2, x_new, mlp1_w, nullptr, nullptr, mlp1_bn, nullptr,
        nullptr, mlp1_b, bnd + 1024, h1T, nullptr, nullptr, nullptr);

    // mlp2: FM h1 (exact bf16 B, 2-MFMA) -> d_out (+x_new base)
    conv_kernel<false, 1024, 3, false, 256><<<dim3(4, 16, 8), blk, 0, stream>>>(
        h1T, nullptr, m2h, m2l, nullptr, nullptr, nullptr, nullptr,
        bnf + 2048, d_out, nullptr, nullptr, x_new, cnts + 3, list3);
    fixup_kernel<true, true, 1024, 3, 256><<<dim3(1024), dim3(64), 0, stream>>>(
        cnts + 3, list3, h1T, mlp2_w, nullptr, nullptr, mlp2_bn, nullptr,
        nullptr, mlp2_b, bnd + 2048, d_out, nullptr, nullptr, x_new);
}

// Round 23
// 363.816 us; speedup vs baseline: 1.1962x; 1.0359x over previous
//
#include <hip/hip_runtime.h>
#include <cstdint>
#include <cstddef>

#define TT 4
#define BB 8
#define CC 256
#define NN 1024
#define HEADS 8
#define DD 32
#define FIXCAP 262144u

typedef __attribute__((ext_vector_type(4))) float f32x4;
typedef __attribute__((ext_vector_type(8))) short s16x8;
typedef unsigned short u16;
typedef unsigned int   u32;

__device__ __forceinline__ u16 bf16_rne(float x) {
    u32 u = __float_as_uint(x);
    return (u16)((u + 0x7FFFu + ((u >> 16) & 1u)) >> 16);
}
__device__ __forceinline__ float bf16f(u16 h) {
    return __uint_as_float(((u32)h) << 16);
}

__global__ __launch_bounds__(64) void zero_counters(u32* c) {
    if (threadIdx.x < 4) c[threadIdx.x] = 0;
}

// Fragment-major index for a [R][K] bf16 plane:
//   FM(r,k) = ((r>>4)*(K/32) + (k>>5))*512 + ((k>>3)&3)*128 + (r&15)*8 + (k&7)

// ---- prep: weights f32 [O][K] -> FM hi/lo bf16 planes ----
template<int OO, int CIN>
__global__ __launch_bounds__(256) void prep_split_fm(
    const float* __restrict__ src, u16* __restrict__ h, u16* __restrict__ l)
{
    const int id = blockIdx.x * 256 + threadIdx.x;
    if (id >= OO * CIN / 8) return;
    const int o = id / (CIN / 8), kq = id % (CIN / 8);
    const float* p = src + (size_t)o * CIN + kq * 8;
    s16x8 hh, ll;
#pragma unroll
    for (int e = 0; e < 8; ++e) {
        float f = p[e];
        u16 hb = bf16_rne(f);
        hh[e] = (short)hb;
        ll[e] = (short)bf16_rne(f - bf16f(hb));
    }
    const int lane = (kq & 3) * 16 + (o & 15);
    const size_t dst = (((size_t)(o >> 4) * (CIN / 32) + (kq >> 2)) * 64 + lane) * 8;
    *(s16x8*)&h[dst] = hh;
    *(s16x8*)&l[dst] = ll;
}

// ---- transpose+split: f32 [m][K][N] -> FM hi/lo planes (for input x only) ----
template<int K, int N>
__global__ __launch_bounds__(256) void trans_split_fm(
    const float* __restrict__ src, u16* __restrict__ dh, u16* __restrict__ dl)
{
    __shared__ float tile[64][65];
    const int tid = threadIdx.x;
    const int n0 = blockIdx.x * 64, k0 = blockIdx.y * 64, m = blockIdx.z;
    for (int i = tid; i < 4096; i += 256) {
        int kk = i >> 6, nn = i & 63;
        tile[kk][nn] = src[((size_t)m * K + k0 + kk) * N + n0 + nn];
    }
    __syncthreads();
    const size_t plane = (size_t)m * (N / 16) * (K / 32) * 512;
    for (int it = tid; it < 512; it += 256) {
        const int nn = it >> 3, kq = it & 7;
        s16x8 hh, ll;
#pragma unroll
        for (int e = 0; e < 8; ++e) {
            float f = tile[kq * 8 + e][nn];
            u16 hb = bf16_rne(f);
            hh[e] = (short)hb;
            ll[e] = (short)bf16_rne(f - bf16f(hb));
        }
        const int n = n0 + nn;
        const int ks = (k0 >> 5) + (kq >> 2), lk = kq & 3;
        const size_t dst = plane + (((size_t)(n >> 4) * (K / 32) + ks) * 64
                                    + lk * 16 + (n & 15)) * 8;
        *(s16x8*)&dh[dst] = hh;
        *(s16x8*)&dl[dst] = ll;
    }
}

// ---- per-channel BN constants ----
__global__ __launch_bounds__(256) void prep_bn(
    const float* qbn, const float* kbn, const float* vbn, const float* pbn,
    const float* m1bn, const float* m2bn,
    const float* pb, const float* m1b, const float* m2b,
    float2* __restrict__ bnf, double* __restrict__ bnd)
{
    int c = blockIdx.x * 256 + threadIdx.x;
    if (c >= 2304) return;
    const float* bn; int ch, O; double bi = 0.0;
    if (c < 1024) {
        int s = c >> 8; ch = c & 255; O = 256;
        bn = s == 0 ? qbn : s == 1 ? kbn : s == 2 ? vbn : pbn;
        if (s == 3) bi = (double)pb[ch];
    } else if (c < 2048) { ch = c - 1024; O = 1024; bn = m1bn; bi = (double)m1b[ch]; }
    else                 { ch = c - 2048; O = 256;  bn = m2bn; bi = (double)m2b[ch]; }
    double g = (double)bn[0*O+ch], be = (double)bn[1*O+ch];
    double mu = (double)bn[2*O+ch], var = (double)bn[3*O+ch];
    double sd = g / sqrt(var + 1e-5);
    bnf[c] = make_float2((float)sd, (float)((bi - mu) * sd + be));
    bnd[c] = sd;
}

// ---- conv1x1 + BN + LIF: fragment-major direct-global bf16-split MFMA ----
// Round-20 proven core: 2-deep full double-buffer, launch_bounds(256,2).
// OUT_MODE: 0 bf16 spikes [c][n] | 1 proj: f32 x_new [c][n] + FM hi/lo planes
//           (LDS-staged, fused transpose) | 2 bf16 spikes FM-DIRECT | 3 f32+base
template<bool SPLIT_IN, int CIN, int OUT_MODE, bool TRIPLE, int O>
__global__ __launch_bounds__(256, 2) void conv_kernel(
    const u16* __restrict__ XTH, const u16* __restrict__ XTL,
    const u16* __restrict__ WH0, const u16* __restrict__ WL0,
    const u16* __restrict__ WH1, const u16* __restrict__ WL1,
    const u16* __restrict__ WH2, const u16* __restrict__ WL2,
    const float2* __restrict__ bnf,
    void* __restrict__ O0_, void* __restrict__ O1_, void* __restrict__ O2_,
    u16* __restrict__ OutH, u16* __restrict__ OutL,
    const float* __restrict__ base,
    u32* __restrict__ cnt, u32* __restrict__ list)
{
    constexpr float EPS = 3e-4f;
    constexpr u32 OT = TRIPLE ? 12 : O / 64;
    constexpr u32 NWG = OT * 16 * 8;
    constexpr int NS = CIN / 32;
    constexpr u32 KS = (u32)(CIN / 32);
    __shared__ float pre[2 * 64 * 64];
    __shared__ u16 xnst[OUT_MODE == 1 ? 16384 : 4];   // [plane][dt][ntile][och][512]

    const int tid  = threadIdx.x;
    const int lane = tid & 63;
    const int wave = tid >> 6;          // == timestep t
    const int lr   = lane & 15;
    const int lk   = lane >> 4;

    const u32 orig = blockIdx.x + OT * (blockIdx.y + 16u * blockIdx.z);
    const u32 flat = (orig & 7u) * (NWG >> 3) + (orig >> 3);
    const u32 otile = flat % OT;
    const u32 rem   = flat / OT;
    const int n0 = (int)(rem & 15u) * 64;
    const int b  = (int)(rem >> 4);

    int o0, sel;
    const u16 *WH, *WL;
    void* Out_;
    if constexpr (TRIPLE) {
        sel = (int)(otile >> 2);
        o0 = (int)(otile & 3) * 64;
        WH = sel==0?WH0:sel==1?WH1:WH2;  WL = sel==0?WL0:sel==1?WL1:WL2;
        Out_ = sel==0?O0_:sel==1?O1_:O2_;
    } else {
        sel = 0; o0 = (int)otile * 64; WH = WH0; WL = WL0; Out_ = O0_;
    }
    const int cofs = sel * 256;

    f32x4 acc[4][4];
#pragma unroll
    for (int mf = 0; mf < 4; ++mf)
#pragma unroll
        for (int nf = 0; nf < 4; ++nf)
            acc[mf][nf] = (f32x4){0.f, 0.f, 0.f, 0.f};

    u32 afm[4], bfm[4];
#pragma unroll
    for (int mf = 0; mf < 4; ++mf)
        afm[mf] = ((u32)(o0 / 16 + mf) * KS) * 512u + (u32)lane * 8u;
    const u32 xplane = (u32)(wave * BB + b) * (u32)(NN / 16) * KS * 512u;
#pragma unroll
    for (int nf = 0; nf < 4; ++nf)
        bfm[nf] = xplane + ((u32)(n0 / 16 + nf) * KS) * 512u + (u32)lane * 8u;

    struct Frag { s16x8 aH[4], aL[4], bH[4], bL[4]; };
    Frag f0, f1;

    auto loadstep = [&](int ks, Frag& f) {
        const u32 ko = (u32)ks * 512u;
#pragma unroll
        for (int mf = 0; mf < 4; ++mf) {
            f.aH[mf] = *(const s16x8*)&WH[(size_t)(afm[mf] + ko)];
            f.aL[mf] = *(const s16x8*)&WL[(size_t)(afm[mf] + ko)];
        }
#pragma unroll
        for (int nf = 0; nf < 4; ++nf) {
            f.bH[nf] = *(const s16x8*)&XTH[(size_t)(bfm[nf] + ko)];
            if constexpr (SPLIT_IN)
                f.bL[nf] = *(const s16x8*)&XTL[(size_t)(bfm[nf] + ko)];
        }
    };
    auto compute = [&](Frag& f) {
        __builtin_amdgcn_s_setprio(1);
#pragma unroll
        for (int mf = 0; mf < 4; ++mf)
#pragma unroll
            for (int nf = 0; nf < 4; ++nf) {
                acc[mf][nf] = __builtin_amdgcn_mfma_f32_16x16x32_bf16(
                    f.aH[mf], f.bH[nf], acc[mf][nf], 0, 0, 0);
                acc[mf][nf] = __builtin_amdgcn_mfma_f32_16x16x32_bf16(
                    f.aL[mf], f.bH[nf], acc[mf][nf], 0, 0, 0);
                if constexpr (SPLIT_IN)
                    acc[mf][nf] = __builtin_amdgcn_mfma_f32_16x16x32_bf16(
                        f.aH[mf], f.bL[nf], acc[mf][nf], 0, 0, 0);
            }
        __builtin_amdgcn_s_setprio(0);
    };

    loadstep(0, f0);
#pragma unroll
    for (int ks = 0; ks < NS; ++ks) {
        if ((ks & 1) == 0) {
            if (ks + 1 < NS) loadstep(ks + 1, f1);
            compute(f0);
        } else {
            if (ks + 1 < NS) loadstep(ks + 1, f0);
            compute(f1);
        }
    }

    const int nl = tid & 63;
    const int og = wave;

    auto dump = [&](int slot) {
#pragma unroll
        for (int mf = 0; mf < 4; ++mf)
#pragma unroll
            for (int nf = 0; nf < 4; ++nf)
#pragma unroll
                for (int r = 0; r < 4; ++r)
                    pre[(size_t)(slot * 64 + mf * 16 + lk * 4 + r) * 64
                        + nf * 16 + lr] = acc[mf][nf][r];
    };

    float2 sc[16];
#pragma unroll
    for (int i = 0; i < 16; ++i) sc[i] = bnf[cofs + o0 + og * 16 + i];

    unsigned flags = 0;
    float vst[16];
    u32 spA = 0, spB = 0;   // OUT_MODE 2 spike bits

    auto do_round = [&](int tbase) {
#pragma unroll
        for (int i = 0; i < 16; ++i) {
            const int o = o0 + og * 16 + i;
            float v = (tbase == 0) ? 0.f : vst[i];
#pragma unroll
            for (int dt = 0; dt < 2; ++dt) {
                const int t = tbase + dt;
                float val = fmaf(pre[(size_t)(dt * 64 + og * 16 + i) * 64 + nl], sc[i].x, sc[i].y);
                v = v + (val - v) * 0.5f;
                if (fabsf(v - 1.0f) < EPS) flags |= (1u << i);
                float s = (v >= 1.0f) ? 1.f : 0.f;
                if constexpr (OUT_MODE == 2) {
                    const u32 bit = (s > 0.5f) ? 1u : 0u;
                    if (tbase == 0) spA |= bit << (dt * 16 + i);
                    else            spB |= bit << (dt * 16 + i);
                } else {
                    const size_t idx = (((size_t)t * BB + b) * O + o) * NN + n0 + nl;
                    if constexpr (OUT_MODE == 0)
                        ((u16*)Out_)[idx] = (s > 0.5f) ? (u16)0x3F80 : (u16)0;
                    else
                        ((float*)Out_)[idx] = base[idx] + s;
                    if constexpr (OUT_MODE == 1) {
                        const float xn = ((float*)Out_)[idx];
                        const u16 hb = bf16_rne(xn);
                        const int och = (og * 16 + i) >> 5;
                        const int loc = ((dt * 4 + (nl >> 4)) * 2 + och) * 512
                                      + ((o >> 3) & 3) * 128 + (nl & 15) * 8 + (o & 7);
                        xnst[loc] = hb;
                        xnst[8192 + loc] = bf16_rne(xn - bf16f(hb));
                    }
                }
                v *= (1.f - s);
            }
            vst[i] = v;
        }
    };

    auto fmwrite = [&](int tbase) {   // write t-pair FM chunks for both planes
        for (int idx2 = tid; idx2 < 2048; idx2 += 256) {
            const int p = idx2 >> 10, r1 = idx2 & 1023;
            const int dt = r1 >> 9, r2 = r1 & 511;
            const int ntile = r2 >> 7, och = (r2 >> 6) & 1, pos = (r2 & 63) * 8;
            const int t = tbase + dt;
            const size_t gb = (((size_t)(t * BB + b) * (NN / 16) + (n0 / 16 + ntile))
                               * (CC / 32) + (o0 / 32 + och)) * 512 + pos;
            u16* dst = p ? OutL : OutH;
            *(s16x8*)&dst[gb] =
                *(const s16x8*)&xnst[p * 8192 + ((dt * 4 + ntile) * 2 + och) * 512 + pos];
        }
    };

    __syncthreads();
    if (wave < 2) dump(wave);
    __syncthreads();
    do_round(0);
    __syncthreads();
    if (wave >= 2) dump(wave - 2);
    if constexpr (OUT_MODE == 1) fmwrite(0);
    __syncthreads();
    do_round(2);

    if constexpr (OUT_MODE == 1) {
        __syncthreads();
        fmwrite(2);
    }

    if constexpr (OUT_MODE == 2) {
        __syncthreads();
        u16* lds16 = (u16*)pre;
#pragma unroll
        for (int dt = 0; dt < 2; ++dt)
#pragma unroll
            for (int i = 0; i < 16; ++i) {
                const int ol = og * 16 + i;
                const int loc = ((nl >> 4) * 2 + (ol >> 5)) * 512
                              + ((ol >> 3) & 3) * 128 + (nl & 15) * 8 + (ol & 7);
                lds16[dt * 4096 + loc] =
                    ((spA >> (dt * 16 + i)) & 1u) ? (u16)0x3F80 : (u16)0;
                lds16[(2 + dt) * 4096 + loc] =
                    ((spB >> (dt * 16 + i)) & 1u) ? (u16)0x3F80 : (u16)0;
            }
        __syncthreads();
        constexpr u32 KO = (u32)(O / 32);
        for (int idx2 = tid; idx2 < 2048; idx2 += 256) {
            const int t = idx2 >> 9, rem2 = idx2 & 511;
            const int c = rem2 >> 6, pos = (rem2 & 63) * 8;
            const int nt = c >> 1, ob = c & 1;
            const size_t gb = (((size_t)(t * BB + b) * (NN / 16) + (n0 / 16 + nt)) * KO
                               + (o0 / 32 + ob)) * 512 + pos;
            *(s16x8*)&((u16*)Out_)[gb] = *(const s16x8*)&lds16[t * 4096 + c * 512 + pos];
        }
    }

    if (flags) {
#pragma unroll 1
        for (int i = 0; i < 16; ++i) {
            if (!(flags & (1u << i))) continue;
            const int o = o0 + og * 16 + i;
            const u32 ent = ((u32)sel << 23) | ((u32)b << 20) | ((u32)o << 10)
                          | (u32)(n0 + nl);
            const u32 idx = atomicAdd(cnt, 1u);
            if (idx < FIXCAP) list[idx] = ent;
        }
    }
}

// ---- exact f64 fixup: one wave per flagged column, lane-parallel K ----
// OUT_MODE 1 also repairs the fused FM hi/lo planes.
template<bool XE_BF16, bool XE_FM, int CIN, int OUT_MODE, int O>
__global__ __launch_bounds__(64) void fixup_kernel(
    const u32* __restrict__ cnt, const u32* __restrict__ list,
    const void* __restrict__ Xe_,
    const float* __restrict__ Wx0, const float* __restrict__ Wx1,
    const float* __restrict__ Wx2,
    const float* __restrict__ bnr0, const float* __restrict__ bnr1,
    const float* __restrict__ bnr2, const float* __restrict__ bias,
    const double* __restrict__ bnd,
    void* __restrict__ O0_, void* __restrict__ O1_, void* __restrict__ O2_,
    u16* __restrict__ OutH, u16* __restrict__ OutL,
    const float* __restrict__ base)
{
    const u32 c0 = *cnt;
    const u32 count = c0 > FIXCAP ? FIXCAP : c0;
    const int lane = threadIdx.x;
    for (u32 e = blockIdx.x; e < count; e += gridDim.x) {
        const u32 ent = list[e];
        const int n = (int)(ent & 1023u);
        const int o = (int)((ent >> 10) & 1023u);
        const int b = (int)((ent >> 20) & 7u);
        const int sel = (int)(ent >> 23);
        const float* Wx  = sel == 0 ? Wx0  : (sel == 1 ? Wx1  : Wx2);
        const float* bnr = sel == 0 ? bnr0 : (sel == 1 ? bnr1 : bnr2);
        void* Out_ = sel == 0 ? O0_ : (sel == 1 ? O1_ : O2_);
        double p[4] = {0.0, 0.0, 0.0, 0.0};
        for (int k = lane; k < CIN; k += 64) {
            const double w = (double)Wx[(size_t)o * CIN + k];
#pragma unroll
            for (int t = 0; t < 4; ++t) {
                size_t xi;
                if constexpr (XE_FM)
                    xi = (((size_t)(t * BB + b) * (NN / 16) + (n >> 4)) * (CIN / 32)
                          + (k >> 5)) * 512 + ((k >> 3) & 3) * 128 + (n & 15) * 8 + (k & 7);
                else
                    xi = ((size_t)(t * BB + b) * CIN + k) * NN + n;
                double xv;
                if constexpr (XE_BF16) xv = (double)bf16f(((const u16*)Xe_)[xi]);
                else                   xv = (double)((const float*)Xe_)[xi];
                p[t] += w * xv;
            }
        }
#pragma unroll
        for (int off = 32; off; off >>= 1)
#pragma unroll
            for (int t = 0; t < 4; ++t) p[t] += __shfl_down(p[t], off);
        if (lane == 0) {
            const double scale = bnd[(OUT_MODE == 0 ? sel * 256 : 0) + o];
            const double be = (double)bnr[1 * O + o];
            const double mu = (double)bnr[2 * O + o];
            double bi = 0.0;
            if constexpr (OUT_MODE != 0) bi = (double)bias[o];
            double v = 0.0;
#pragma unroll
            for (int t = 0; t < TT; ++t) {
                const double val = (p[t] + bi - mu) * scale + be;
                v = v + (val - v) * 0.5;
                const double sd = (v >= 1.0) ? 1.0 : 0.0;
                if constexpr (OUT_MODE == 2) {
                    const size_t fm = (((size_t)(t * BB + b) * (NN / 16) + (n >> 4))
                                       * (O / 32) + (o >> 5)) * 512
                                    + ((o >> 3) & 3) * 128 + (n & 15) * 8 + (o & 7);
                    ((u16*)Out_)[fm] = (sd > 0.5) ? (u16)0x3F80 : (u16)0;
                } else {
                    const size_t idx = (((size_t)t * BB + b) * O + o) * NN + n;
                    if constexpr (OUT_MODE == 0)
                        ((u16*)Out_)[idx] = (sd > 0.5) ? (u16)0x3F80 : (u16)0;
                    else
                        ((float*)Out_)[idx] = (float)((double)base[idx] + sd);
                    if constexpr (OUT_MODE == 1) {
                        const float xn = ((float*)Out_)[idx];
                        const u16 hb = bf16_rne(xn);
                        const size_t fm = (((size_t)(t * BB + b) * (NN / 16) + (n >> 4))
                                           * (CC / 32) + (o >> 5)) * 512
                                        + ((o >> 3) & 3) * 128 + (n & 15) * 8 + (o & 7);
                        OutH[fm] = hb;
                        OutL[fm] = bf16_rne(xn - bf16f(hb));
                    }
                }
                v = v * (1.0 - sd);
            }
        }
    }
}

// ---- kv via MFMA: one wave per (t,b,h); exact 0/1 bf16 spikes ----
__global__ __launch_bounds__(256) void kv_mfma(
    const u16* __restrict__ k_s, const u16* __restrict__ v_s,
    float* __restrict__ kv)
{
    const int lane = threadIdx.x & 63;
    const int wave = threadIdx.x >> 6;
    const int unit = blockIdx.x * 4 + wave;
    const int h = unit & 7;
    const int m = unit >> 3;
    const int lr = lane & 15, lk = lane >> 4;
    const size_t base = ((size_t)m * CC + h * DD) * NN;

    f32x4 acc[2][2];
#pragma unroll
    for (int mt = 0; mt < 2; ++mt)
#pragma unroll
        for (int nt = 0; nt < 2; ++nt)
            acc[mt][nt] = (f32x4){0.f, 0.f, 0.f, 0.f};

#pragma unroll 4
    for (int ks = 0; ks < 32; ++ks) {
        s16x8 a[2], bf[2];
#pragma unroll
        for (int mt = 0; mt < 2; ++mt)
            a[mt] = *(const s16x8*)&k_s[base + (size_t)(mt * 16 + lr) * NN
                                         + ks * 32 + lk * 8];
#pragma unroll
        for (int nt = 0; nt < 2; ++nt)
            bf[nt] = *(const s16x8*)&v_s[base + (size_t)(nt * 16 + lr) * NN
                                          + ks * 32 + lk * 8];
#pragma unroll
        for (int mt = 0; mt < 2; ++mt)
#pragma unroll
            for (int nt = 0; nt < 2; ++nt)
                acc[mt][nt] = __builtin_amdgcn_mfma_f32_16x16x32_bf16(
                    a[mt], bf[nt], acc[mt][nt], 0, 0, 0);
    }
#pragma unroll
    for (int mt = 0; mt < 2; ++mt)
#pragma unroll
        for (int nt = 0; nt < 2; ++nt)
#pragma unroll
            for (int r = 0; r < 4; ++r)
                kv[(size_t)unit * 1024 + (mt * 16 + lk * 4 + r) * 32
                   + nt * 16 + lr] = acc[mt][nt][r];
}

// a = 0.125 * q @ kv -> LIF(0.5); LDS-staged q; writes natural a_s AND FM aT.
// Block: 64 n x 32 e (one h) x 1 b; block owns FM chunks (4 ntile x chunk h).
__global__ __launch_bounds__(256) void attn_a_lif(
    const u16* __restrict__ q_s, const float* __restrict__ kv,
    u16* __restrict__ a_s, u16* __restrict__ aT)
{
    __shared__ u16 qt[TT][32][64];       // 16 KB
    __shared__ float kvs[TT][32][32];    // 16 KB
    __shared__ u16 ast[TT][4][512];      // 16 KB FM stage
    const int tid = threadIdx.x;
    const int n0 = blockIdx.x * 64;
    const int h  = blockIdx.y;
    const int b  = blockIdx.z;

    for (int i = tid; i < TT * 32 * 64 / 4; i += 256) {
        const int t = i >> 9, rem = i & 511;
        const int d = rem >> 4, n4 = rem & 15;
        const size_t g = (((size_t)t * BB + b) * CC + h * DD + d) * NN + n0 + n4 * 4;
        *(ushort4*)&qt[t][d][n4 * 4] = *(const ushort4*)&q_s[g];
    }
    for (int i = tid; i < TT * 32 * 32 / 4; i += 256) {
        const int t = i >> 8, rem = i & 255;
        const int d = rem >> 3, e4 = rem & 7;
        const size_t g = (((size_t)t * BB + b) * HEADS + h) * 1024 + d * 32 + e4 * 4;
        *(float4*)&kvs[t][d][e4 * 4] = *(const float4*)&kv[g];
    }
    __syncthreads();

    const int nl = tid & 63;
    const int eg = tid >> 6;
#pragma unroll
    for (int ei = 0; ei < 8; ++ei) {
        const int e = eg * 8 + ei;
        float val[TT];
#pragma unroll
        for (int t = 0; t < TT; ++t) {
            float s = 0.f;
#pragma unroll 8
            for (int d = 0; d < 32; ++d)
                s += bf16f(qt[t][d][nl]) * kvs[t][d][e];
            val[t] = s * 0.125f;
        }
        float v = 0.f;
#pragma unroll
        for (int t = 0; t < TT; ++t) {
            v = v + (val[t] - v) * 0.5f;
            float s = (v >= 0.5f) ? 1.f : 0.f;
            const u16 sp = (s > 0.5f) ? (u16)0x3F80 : (u16)0;
            a_s[(((size_t)t * BB + b) * CC + h * DD + e) * NN + n0 + nl] = sp;
            ast[t][nl >> 4][((e >> 3) & 3) * 128 + (nl & 15) * 8 + (e & 7)] = sp;
            v = v * (1.f - s);
        }
    }
    __syncthreads();
    // coalesced FM write: 4t x 4 ntile x 512
    for (int i = tid; i < 1024; i += 256) {
        const int t = i >> 8, r2 = i & 255;
        const int ntile = r2 >> 6, pos = (r2 & 63) * 8;
        const size_t gb = (((size_t)(t * BB + b) * (NN / 16) + (n0 / 16 + ntile))
                           * (CC / 32) + h) * 512 + pos;
        *(s16x8*)&aT[gb] = *(const s16x8*)&ast[t][ntile][pos];
    }
}

extern "C" void kernel_launch(void* const* d_in, const int* in_sizes, int n_in,
                              void* d_out, int out_size, void* d_ws, size_t ws_size,
                              hipStream_t stream)
{
    const float* x       = (const float*)d_in[0];
    const float* q_w     = (const float*)d_in[1];
    const float* q_bn    = (const float*)d_in[2];
    const float* k_w     = (const float*)d_in[3];
    const float* k_bn    = (const float*)d_in[4];
    const float* v_w     = (const float*)d_in[5];
    const float* v_bn    = (const float*)d_in[6];
    const float* proj_w  = (const float*)d_in[7];
    const float* proj_b  = (const float*)d_in[8];
    const float* proj_bn = (const float*)d_in[9];
    const float* mlp1_w  = (const float*)d_in[10];
    const float* mlp1_b  = (const float*)d_in[11];
    const float* mlp1_bn = (const float*)d_in[12];
    const float* mlp2_w  = (const float*)d_in[13];
    const float* mlp2_b  = (const float*)d_in[14];
    const float* mlp2_bn = (const float*)d_in[15];

    const size_t SZ = (size_t)TT * BB * CC * NN;   // 8388608
    const size_t U = SZ * 2;                       // 16.75 MB unit
    char* ws = (char*)d_ws;
    u16*   xTh  = (u16*)(ws);              // FM x planes; dead after qkv
    u16*   xTl  = (u16*)(ws + U);
    u16*   q_s  = (u16*)(ws + 2*U);        // natural [c][n]
    u16*   k_s  = (u16*)(ws + 3*U);
    u16*   v_s  = (u16*)(ws + 4*U);
    u16*   a_s  = (u16*)(ws);              // overlays xTh (attn out, natural)
    u16*   aT   = (u16*)(ws + U);          // overlays xTl (FM of a_s)
    float* x_new= (float*)(ws + 2*U);      // overlays q_s,k_s (natural f32)
    u16*   xnTh = (u16*)(ws + 4*U);        // overlays v_s (FM planes)
    u16*   xnTl = (u16*)(ws + 5*U);
    u16*   h1T  = (u16*)(ws + 10*U);       // FM spikes (written directly)
    char* wp = ws + 14*U;
    float* kvb = (float*)wp; wp += (size_t)262144 * 4;
    u16* qh  = (u16*)wp; wp += 65536 * 2;  u16* ql  = (u16*)wp; wp += 65536 * 2;
    u16* kh  = (u16*)wp; wp += 65536 * 2;  u16* kl  = (u16*)wp; wp += 65536 * 2;
    u16* vh  = (u16*)wp; wp += 65536 * 2;  u16* vl  = (u16*)wp; wp += 65536 * 2;
    u16* ph  = (u16*)wp; wp += 65536 * 2;  u16* pl  = (u16*)wp; wp += 65536 * 2;
    u16* m1h = (u16*)wp; wp += 262144 * 2; u16* m1l = (u16*)wp; wp += 262144 * 2;
    u16* m2h = (u16*)wp; wp += 262144 * 2; u16* m2l = (u16*)wp; wp += 262144 * 2;
    float2* bnf = (float2*)wp; wp += 2304 * 8;
    double* bnd = (double*)wp; wp += 2304 * 8;
    u32* cnts = (u32*)wp; wp += 4 * 4;
    u32* list0 = (u32*)wp; wp += FIXCAP * 4;
    u32* list1 = (u32*)wp; wp += FIXCAP * 4;
    u32* list2 = (u32*)wp; wp += FIXCAP * 4;
    u32* list3 = (u32*)wp;

    dim3 blk(256);

    zero_counters<<<dim3(1), dim3(64), 0, stream>>>(cnts);

    // prep: weights -> FM hi/lo; x -> FM hi/lo; BN constants
    prep_split_fm<256, 256>  <<<dim3(32),  blk, 0, stream>>>(q_w,    qh,  ql);
    prep_split_fm<256, 256>  <<<dim3(32),  blk, 0, stream>>>(k_w,    kh,  kl);
    prep_split_fm<256, 256>  <<<dim3(32),  blk, 0, stream>>>(v_w,    vh,  vl);
    prep_split_fm<256, 256>  <<<dim3(32),  blk, 0, stream>>>(proj_w, ph,  pl);
    prep_split_fm<1024, 256> <<<dim3(128), blk, 0, stream>>>(mlp1_w, m1h, m1l);
    prep_split_fm<256, 1024> <<<dim3(128), blk, 0, stream>>>(mlp2_w, m2h, m2l);
    trans_split_fm<256, 1024><<<dim3(16, 4, 32), blk, 0, stream>>>(x, xTh, xTl);
    prep_bn<<<dim3(9), blk, 0, stream>>>(q_bn, k_bn, v_bn, proj_bn, mlp1_bn,
                                         mlp2_bn, proj_b, mlp1_b, mlp2_b, bnf, bnd);

    // qkv: FM x -> bf16 spike trains [c][n]
    conv_kernel<true, 256, 0, true, 256><<<dim3(12, 16, 8), blk, 0, stream>>>(
        xTh, xTl, qh, ql, kh, kl, vh, vl, bnf, q_s, k_s, v_s,
        nullptr, nullptr, nullptr, cnts + 0, list0);
    fixup_kernel<false, false, 256, 0, 256><<<dim3(1024), dim3(64), 0, stream>>>(
        cnts + 0, list0, x, q_w, k_w, v_w, q_bn, k_bn, v_bn, nullptr, bnd,
        q_s, k_s, v_s, nullptr, nullptr, nullptr);

    // attention (exact): kv via MFMA, then a + LIF (writes a_s AND FM aT)
    kv_mfma<<<dim3(64), blk, 0, stream>>>(k_s, v_s, kvb);
    attn_a_lif<<<dim3(16, 8, 8), blk, 0, stream>>>(q_s, kvb, a_s, aT);

    // proj: FM a -> x_new f32 [c][n] + fused FM hi/lo planes (+x base)
    conv_kernel<false, 256, 1, false, 256><<<dim3(4, 16, 8), blk, 0, stream>>>(
        aT, nullptr, ph, pl, nullptr, nullptr, nullptr, nullptr,
        bnf + 768, x_new, nullptr, nullptr, xnTh, xnTl, x, cnts + 1, list1);
    fixup_kernel<true, false, 256, 1, 256><<<dim3(1024), dim3(64), 0, stream>>>(
        cnts + 1, list1, a_s, proj_w, nullptr, nullptr, proj_bn, nullptr,
        nullptr, proj_b, bnd + 768, x_new, nullptr, nullptr, xnTh, xnTl, x);

    // mlp1: FM x_new -> h1T FM spikes DIRECTLY
    conv_kernel<true, 256, 2, false, 1024><<<dim3(16, 16, 8), blk, 0, stream>>>(
        xnTh, xnTl, m1h, m1l, nullptr, nullptr, nullptr, nullptr,
        bnf + 1024, h1T, nullptr, nullptr, nullptr, nullptr, nullptr,
        cnts + 2, list2);
    fixup_kernel<false, false, 256, 2, 1024><<<dim3(1024), dim3(64), 0, stream>>>(
        cnts + 2, list2, x_new, mlp1_w, nullptr, nullptr, mlp1_bn, nullptr,
        nullptr, mlp1_b, bnd + 1024, h1T, nullptr, nullptr, nullptr, nullptr,
        nullptr);

    // mlp2: FM h1 -> d_out (+x_new base)
    conv_kernel<false, 1024, 3, false, 256><<<dim3(4, 16, 8), blk, 0, stream>>>(
        h1T, nullptr, m2h, m2l, nullptr, nullptr, nullptr, nullptr,
        bnf + 2048, d_out, nullptr, nullptr, nullptr, nullptr, x_new,
        cnts + 3, list3);
    fixup_kernel<true, true, 1024, 3, 256><<<dim3(1024), dim3(64), 0, stream>>>(
        cnts + 3, list3, h1T, mlp2_w, nullptr, nullptr, mlp2_bn, nullptr,
        nullptr, mlp2_b, bnd + 2048, d_out, nullptr, nullptr, nullptr, nullptr,
        x_new);
}

// Round 24
// 352.407 us; speedup vs baseline: 1.2349x; 1.0324x over previous
//
#include <hip/hip_runtime.h>
#include <cstdint>
#include <cstddef>

#define TT 4
#define BB 8
#define CC 256
#define NN 1024
#define HEADS 8
#define DD 32
#define FIXCAP 262144u

typedef __attribute__((ext_vector_type(4))) float f32x4;
typedef __attribute__((ext_vector_type(8))) short s16x8;
typedef unsigned short u16;
typedef unsigned int   u32;

__device__ __forceinline__ u16 bf16_rne(float x) {
    u32 u = __float_as_uint(x);
    return (u16)((u + 0x7FFFu + ((u >> 16) & 1u)) >> 16);
}
__device__ __forceinline__ float bf16f(u16 h) {
    return __uint_as_float(((u32)h) << 16);
}

// Fragment-major index for a [R][K] bf16 plane:
//   FM(r,k) = ((r>>4)*(K/32) + (k>>5))*512 + ((k>>3)&3)*128 + (r&15)*8 + (k&7)

// ---- prep: ALL weights f32 -> FM hi/lo bf16 planes, one dispatch ----
// flattened id: [0,8192) q | [8192,16384) k | [16384,24576) v | [24576,32768) proj
//               [32768,65536) mlp1 (CIN=256) | [65536,98304) mlp2 (CIN=1024)
__global__ __launch_bounds__(256) void prep_weights_all(
    const float* __restrict__ qw, const float* __restrict__ kw,
    const float* __restrict__ vw, const float* __restrict__ pw,
    const float* __restrict__ m1w, const float* __restrict__ m2w,
    u16* __restrict__ qh, u16* __restrict__ ql,
    u16* __restrict__ kh, u16* __restrict__ kl,
    u16* __restrict__ vh, u16* __restrict__ vl,
    u16* __restrict__ ph, u16* __restrict__ pl,
    u16* __restrict__ m1h, u16* __restrict__ m1l,
    u16* __restrict__ m2h, u16* __restrict__ m2l)
{
    const int id = blockIdx.x * 256 + threadIdx.x;
    if (id >= 98304) return;
    const float* src; u16 *dh, *dl; int CIN, lid;
    if (id < 32768) {
        const int s = id >> 13; lid = id & 8191; CIN = 256;
        src = s == 0 ? qw : s == 1 ? kw : s == 2 ? vw : pw;
        dh  = s == 0 ? qh : s == 1 ? kh : s == 2 ? vh : ph;
        dl  = s == 0 ? ql : s == 1 ? kl : s == 2 ? vl : pl;
    } else if (id < 65536) { lid = id - 32768; CIN = 256;  src = m1w; dh = m1h; dl = m1l; }
    else                   { lid = id - 65536; CIN = 1024; src = m2w; dh = m2h; dl = m2l; }
    const int o = lid / (CIN / 8), kq = lid % (CIN / 8);
    const float* p = src + (size_t)o * CIN + kq * 8;
    s16x8 hh, ll;
#pragma unroll
    for (int e = 0; e < 8; ++e) {
        float f = p[e];
        u16 hb = bf16_rne(f);
        hh[e] = (short)hb;
        ll[e] = (short)bf16_rne(f - bf16f(hb));
    }
    const int lane = (kq & 3) * 16 + (o & 15);
    const size_t dst = (((size_t)(o >> 4) * (CIN / 32) + (kq >> 2)) * 64 + lane) * 8;
    *(s16x8*)&dh[dst] = hh;
    *(s16x8*)&dl[dst] = ll;
}

// ---- transpose+split: f32 [m][K][N] -> FM hi/lo planes (input x only) ----
template<int K, int N>
__global__ __launch_bounds__(256) void trans_split_fm(
    const float* __restrict__ src, u16* __restrict__ dh, u16* __restrict__ dl)
{
    __shared__ float tile[64][65];
    const int tid = threadIdx.x;
    const int n0 = blockIdx.x * 64, k0 = blockIdx.y * 64, m = blockIdx.z;
    for (int i = tid; i < 4096; i += 256) {
        int kk = i >> 6, nn = i & 63;
        tile[kk][nn] = src[((size_t)m * K + k0 + kk) * N + n0 + nn];
    }
    __syncthreads();
    const size_t plane = (size_t)m * (N / 16) * (K / 32) * 512;
    for (int it = tid; it < 512; it += 256) {
        const int nn = it >> 3, kq = it & 7;
        s16x8 hh, ll;
#pragma unroll
        for (int e = 0; e < 8; ++e) {
            float f = tile[kq * 8 + e][nn];
            u16 hb = bf16_rne(f);
            hh[e] = (short)hb;
            ll[e] = (short)bf16_rne(f - bf16f(hb));
        }
        const int n = n0 + nn;
        const int ks = (k0 >> 5) + (kq >> 2), lk = kq & 3;
        const size_t dst = plane + (((size_t)(n >> 4) * (K / 32) + ks) * 64
                                    + lk * 16 + (n & 15)) * 8;
        *(s16x8*)&dh[dst] = hh;
        *(s16x8*)&dl[dst] = ll;
    }
}

// ---- per-channel BN constants + counter zeroing (fused) ----
__global__ __launch_bounds__(256) void prep_bn(
    const float* qbn, const float* kbn, const float* vbn, const float* pbn,
    const float* m1bn, const float* m2bn,
    const float* pb, const float* m1b, const float* m2b,
    float2* __restrict__ bnf, double* __restrict__ bnd,
    u32* __restrict__ cnts)
{
    if (blockIdx.x == 0 && threadIdx.x < 4) cnts[threadIdx.x] = 0;
    int c = blockIdx.x * 256 + threadIdx.x;
    if (c >= 2304) return;
    const float* bn; int ch, O; double bi = 0.0;
    if (c < 1024) {
        int s = c >> 8; ch = c & 255; O = 256;
        bn = s == 0 ? qbn : s == 1 ? kbn : s == 2 ? vbn : pbn;
        if (s == 3) bi = (double)pb[ch];
    } else if (c < 2048) { ch = c - 1024; O = 1024; bn = m1bn; bi = (double)m1b[ch]; }
    else                 { ch = c - 2048; O = 256;  bn = m2bn; bi = (double)m2b[ch]; }
    double g = (double)bn[0*O+ch], be = (double)bn[1*O+ch];
    double mu = (double)bn[2*O+ch], var = (double)bn[3*O+ch];
    double sd = g / sqrt(var + 1e-5);
    bnf[c] = make_float2((float)sd, (float)((bi - mu) * sd + be));
    bnd[c] = sd;
}

// ---- conv1x1 + BN + LIF: fragment-major direct-global bf16-split MFMA ----
// Round-20 proven core: 2-deep full double-buffer, launch_bounds(256,2).
// OUT_MODE: 0 bf16 spikes [c][n] | 1 proj: f32 x_new [c][n] + FM hi/lo planes
//           (fused transpose) | 2 bf16 spikes FM-DIRECT | 3 f32+base
template<bool SPLIT_IN, int CIN, int OUT_MODE, bool TRIPLE, int O>
__global__ __launch_bounds__(256, 2) void conv_kernel(
    const u16* __restrict__ XTH, const u16* __restrict__ XTL,
    const u16* __restrict__ WH0, const u16* __restrict__ WL0,
    const u16* __restrict__ WH1, const u16* __restrict__ WL1,
    const u16* __restrict__ WH2, const u16* __restrict__ WL2,
    const float2* __restrict__ bnf,
    void* __restrict__ O0_, void* __restrict__ O1_, void* __restrict__ O2_,
    u16* __restrict__ OutH, u16* __restrict__ OutL,
    const float* __restrict__ base,
    u32* __restrict__ cnt, u32* __restrict__ list)
{
    constexpr float EPS = 3e-4f;
    constexpr u32 OT = TRIPLE ? 12 : O / 64;
    constexpr u32 NWG = OT * 16 * 8;
    constexpr int NS = CIN / 32;
    constexpr u32 KS = (u32)(CIN / 32);
    __shared__ float pre[2 * 64 * 64];
    __shared__ u16 xnst[OUT_MODE == 1 ? 16384 : 4];

    const int tid  = threadIdx.x;
    const int lane = tid & 63;
    const int wave = tid >> 6;          // == timestep t
    const int lr   = lane & 15;
    const int lk   = lane >> 4;

    const u32 orig = blockIdx.x + OT * (blockIdx.y + 16u * blockIdx.z);
    const u32 flat = (orig & 7u) * (NWG >> 3) + (orig >> 3);
    const u32 otile = flat % OT;
    const u32 rem   = flat / OT;
    const int n0 = (int)(rem & 15u) * 64;
    const int b  = (int)(rem >> 4);

    int o0, sel;
    const u16 *WH, *WL;
    void* Out_;
    if constexpr (TRIPLE) {
        sel = (int)(otile >> 2);
        o0 = (int)(otile & 3) * 64;
        WH = sel==0?WH0:sel==1?WH1:WH2;  WL = sel==0?WL0:sel==1?WL1:WL2;
        Out_ = sel==0?O0_:sel==1?O1_:O2_;
    } else {
        sel = 0; o0 = (int)otile * 64; WH = WH0; WL = WL0; Out_ = O0_;
    }
    const int cofs = sel * 256;

    f32x4 acc[4][4];
#pragma unroll
    for (int mf = 0; mf < 4; ++mf)
#pragma unroll
        for (int nf = 0; nf < 4; ++nf)
            acc[mf][nf] = (f32x4){0.f, 0.f, 0.f, 0.f};

    u32 afm[4], bfm[4];
#pragma unroll
    for (int mf = 0; mf < 4; ++mf)
        afm[mf] = ((u32)(o0 / 16 + mf) * KS) * 512u + (u32)lane * 8u;
    const u32 xplane = (u32)(wave * BB + b) * (u32)(NN / 16) * KS * 512u;
#pragma unroll
    for (int nf = 0; nf < 4; ++nf)
        bfm[nf] = xplane + ((u32)(n0 / 16 + nf) * KS) * 512u + (u32)lane * 8u;

    struct Frag { s16x8 aH[4], aL[4], bH[4], bL[4]; };
    Frag f0, f1;

    auto loadstep = [&](int ks, Frag& f) {
        const u32 ko = (u32)ks * 512u;
#pragma unroll
        for (int mf = 0; mf < 4; ++mf) {
            f.aH[mf] = *(const s16x8*)&WH[(size_t)(afm[mf] + ko)];
            f.aL[mf] = *(const s16x8*)&WL[(size_t)(afm[mf] + ko)];
        }
#pragma unroll
        for (int nf = 0; nf < 4; ++nf) {
            f.bH[nf] = *(const s16x8*)&XTH[(size_t)(bfm[nf] + ko)];
            if constexpr (SPLIT_IN)
                f.bL[nf] = *(const s16x8*)&XTL[(size_t)(bfm[nf] + ko)];
        }
    };
    auto compute = [&](Frag& f) {
        __builtin_amdgcn_s_setprio(1);
#pragma unroll
        for (int mf = 0; mf < 4; ++mf)
#pragma unroll
            for (int nf = 0; nf < 4; ++nf) {
                acc[mf][nf] = __builtin_amdgcn_mfma_f32_16x16x32_bf16(
                    f.aH[mf], f.bH[nf], acc[mf][nf], 0, 0, 0);
                acc[mf][nf] = __builtin_amdgcn_mfma_f32_16x16x32_bf16(
                    f.aL[mf], f.bH[nf], acc[mf][nf], 0, 0, 0);
                if constexpr (SPLIT_IN)
                    acc[mf][nf] = __builtin_amdgcn_mfma_f32_16x16x32_bf16(
                        f.aH[mf], f.bL[nf], acc[mf][nf], 0, 0, 0);
            }
        __builtin_amdgcn_s_setprio(0);
    };

    loadstep(0, f0);
#pragma unroll
    for (int ks = 0; ks < NS; ++ks) {
        if ((ks & 1) == 0) {
            if (ks + 1 < NS) loadstep(ks + 1, f1);
            compute(f0);
        } else {
            if (ks + 1 < NS) loadstep(ks + 1, f0);
            compute(f1);
        }
    }

    const int nl = tid & 63;
    const int og = wave;

    auto dump = [&](int slot) {
#pragma unroll
        for (int mf = 0; mf < 4; ++mf)
#pragma unroll
            for (int nf = 0; nf < 4; ++nf)
#pragma unroll
                for (int r = 0; r < 4; ++r)
                    pre[(size_t)(slot * 64 + mf * 16 + lk * 4 + r) * 64
                        + nf * 16 + lr] = acc[mf][nf][r];
    };

    float2 sc[16];
#pragma unroll
    for (int i = 0; i < 16; ++i) sc[i] = bnf[cofs + o0 + og * 16 + i];

    unsigned flags = 0;
    float vst[16];
    u32 spA = 0, spB = 0;

    auto do_round = [&](int tbase) {
#pragma unroll
        for (int i = 0; i < 16; ++i) {
            const int o = o0 + og * 16 + i;
            float v = (tbase == 0) ? 0.f : vst[i];
#pragma unroll
            for (int dt = 0; dt < 2; ++dt) {
                const int t = tbase + dt;
                float val = fmaf(pre[(size_t)(dt * 64 + og * 16 + i) * 64 + nl], sc[i].x, sc[i].y);
                v = v + (val - v) * 0.5f;
                if (fabsf(v - 1.0f) < EPS) flags |= (1u << i);
                float s = (v >= 1.0f) ? 1.f : 0.f;
                if constexpr (OUT_MODE == 2) {
                    const u32 bit = (s > 0.5f) ? 1u : 0u;
                    if (tbase == 0) spA |= bit << (dt * 16 + i);
                    else            spB |= bit << (dt * 16 + i);
                } else {
                    const size_t idx = (((size_t)t * BB + b) * O + o) * NN + n0 + nl;
                    if constexpr (OUT_MODE == 0)
                        ((u16*)Out_)[idx] = (s > 0.5f) ? (u16)0x3F80 : (u16)0;
                    else
                        ((float*)Out_)[idx] = base[idx] + s;
                    if constexpr (OUT_MODE == 1) {
                        const float xn = ((float*)Out_)[idx];
                        const u16 hb = bf16_rne(xn);
                        const int och = (og * 16 + i) >> 5;
                        const int loc = ((dt * 4 + (nl >> 4)) * 2 + och) * 512
                                      + ((o >> 3) & 3) * 128 + (nl & 15) * 8 + (o & 7);
                        xnst[loc] = hb;
                        xnst[8192 + loc] = bf16_rne(xn - bf16f(hb));
                    }
                }
                v *= (1.f - s);
            }
            vst[i] = v;
        }
    };

    auto fmwrite = [&](int tbase) {
        for (int idx2 = tid; idx2 < 2048; idx2 += 256) {
            const int p = idx2 >> 10, r1 = idx2 & 1023;
            const int dt = r1 >> 9, r2 = r1 & 511;
            const int ntile = r2 >> 7, och = (r2 >> 6) & 1, pos = (r2 & 63) * 8;
            const int t = tbase + dt;
            const size_t gb = (((size_t)(t * BB + b) * (NN / 16) + (n0 / 16 + ntile))
                               * (CC / 32) + (o0 / 32 + och)) * 512 + pos;
            u16* dst = p ? OutL : OutH;
            *(s16x8*)&dst[gb] =
                *(const s16x8*)&xnst[p * 8192 + ((dt * 4 + ntile) * 2 + och) * 512 + pos];
        }
    };

    __syncthreads();
    if (wave < 2) dump(wave);
    __syncthreads();
    do_round(0);
    __syncthreads();
    if (wave >= 2) dump(wave - 2);
    if constexpr (OUT_MODE == 1) fmwrite(0);
    __syncthreads();
    do_round(2);

    if constexpr (OUT_MODE == 1) {
        __syncthreads();
        fmwrite(2);
    }

    if constexpr (OUT_MODE == 2) {
        __syncthreads();
        u16* lds16 = (u16*)pre;
#pragma unroll
        for (int dt = 0; dt < 2; ++dt)
#pragma unroll
            for (int i = 0; i < 16; ++i) {
                const int ol = og * 16 + i;
                const int loc = ((nl >> 4) * 2 + (ol >> 5)) * 512
                              + ((ol >> 3) & 3) * 128 + (nl & 15) * 8 + (ol & 7);
                lds16[dt * 4096 + loc] =
                    ((spA >> (dt * 16 + i)) & 1u) ? (u16)0x3F80 : (u16)0;
                lds16[(2 + dt) * 4096 + loc] =
                    ((spB >> (dt * 16 + i)) & 1u) ? (u16)0x3F80 : (u16)0;
            }
        __syncthreads();
        constexpr u32 KO = (u32)(O / 32);
        for (int idx2 = tid; idx2 < 2048; idx2 += 256) {
            const int t = idx2 >> 9, rem2 = idx2 & 511;
            const int c = rem2 >> 6, pos = (rem2 & 63) * 8;
            const int nt = c >> 1, ob = c & 1;
            const size_t gb = (((size_t)(t * BB + b) * (NN / 16) + (n0 / 16 + nt)) * KO
                               + (o0 / 32 + ob)) * 512 + pos;
            *(s16x8*)&((u16*)Out_)[gb] = *(const s16x8*)&lds16[t * 4096 + c * 512 + pos];
        }
    }

    if (flags) {
#pragma unroll 1
        for (int i = 0; i < 16; ++i) {
            if (!(flags & (1u << i))) continue;
            const int o = o0 + og * 16 + i;
            const u32 ent = ((u32)sel << 23) | ((u32)b << 20) | ((u32)o << 10)
                          | (u32)(n0 + nl);
            const u32 idx = atomicAdd(cnt, 1u);
            if (idx < FIXCAP) list[idx] = ent;
        }
    }
}

// ---- exact f64 fixup: one wave per flagged column, lane-parallel K ----
template<bool XE_BF16, bool XE_FM, int CIN, int OUT_MODE, int O>
__global__ __launch_bounds__(64) void fixup_kernel(
    const u32* __restrict__ cnt, const u32* __restrict__ list,
    const void* __restrict__ Xe_,
    const float* __restrict__ Wx0, const float* __restrict__ Wx1,
    const float* __restrict__ Wx2,
    const float* __restrict__ bnr0, const float* __restrict__ bnr1,
    const float* __restrict__ bnr2, const float* __restrict__ bias,
    const double* __restrict__ bnd,
    void* __restrict__ O0_, void* __restrict__ O1_, void* __restrict__ O2_,
    u16* __restrict__ OutH, u16* __restrict__ OutL,
    const float* __restrict__ base)
{
    const u32 c0 = *cnt;
    const u32 count = c0 > FIXCAP ? FIXCAP : c0;
    const int lane = threadIdx.x;
    for (u32 e = blockIdx.x; e < count; e += gridDim.x) {
        const u32 ent = list[e];
        const int n = (int)(ent & 1023u);
        const int o = (int)((ent >> 10) & 1023u);
        const int b = (int)((ent >> 20) & 7u);
        const int sel = (int)(ent >> 23);
        const float* Wx  = sel == 0 ? Wx0  : (sel == 1 ? Wx1  : Wx2);
        const float* bnr = sel == 0 ? bnr0 : (sel == 1 ? bnr1 : bnr2);
        void* Out_ = sel == 0 ? O0_ : (sel == 1 ? O1_ : O2_);
        double p[4] = {0.0, 0.0, 0.0, 0.0};
        for (int k = lane; k < CIN; k += 64) {
            const double w = (double)Wx[(size_t)o * CIN + k];
#pragma unroll
            for (int t = 0; t < 4; ++t) {
                size_t xi;
                if constexpr (XE_FM)
                    xi = (((size_t)(t * BB + b) * (NN / 16) + (n >> 4)) * (CIN / 32)
                          + (k >> 5)) * 512 + ((k >> 3) & 3) * 128 + (n & 15) * 8 + (k & 7);
                else
                    xi = ((size_t)(t * BB + b) * CIN + k) * NN + n;
                double xv;
                if constexpr (XE_BF16) xv = (double)bf16f(((const u16*)Xe_)[xi]);
                else                   xv = (double)((const float*)Xe_)[xi];
                p[t] += w * xv;
            }
        }
#pragma unroll
        for (int off = 32; off; off >>= 1)
#pragma unroll
            for (int t = 0; t < 4; ++t) p[t] += __shfl_down(p[t], off);
        if (lane == 0) {
            const double scale = bnd[(OUT_MODE == 0 ? sel * 256 : 0) + o];
            const double be = (double)bnr[1 * O + o];
            const double mu = (double)bnr[2 * O + o];
            double bi = 0.0;
            if constexpr (OUT_MODE != 0) bi = (double)bias[o];
            double v = 0.0;
#pragma unroll
            for (int t = 0; t < TT; ++t) {
                const double val = (p[t] + bi - mu) * scale + be;
                v = v + (val - v) * 0.5;
                const double sd = (v >= 1.0) ? 1.0 : 0.0;
                if constexpr (OUT_MODE == 2) {
                    const size_t fm = (((size_t)(t * BB + b) * (NN / 16) + (n >> 4))
                                       * (O / 32) + (o >> 5)) * 512
                                    + ((o >> 3) & 3) * 128 + (n & 15) * 8 + (o & 7);
                    ((u16*)Out_)[fm] = (sd > 0.5) ? (u16)0x3F80 : (u16)0;
                } else {
                    const size_t idx = (((size_t)t * BB + b) * O + o) * NN + n;
                    if constexpr (OUT_MODE == 0)
                        ((u16*)Out_)[idx] = (sd > 0.5) ? (u16)0x3F80 : (u16)0;
                    else
                        ((float*)Out_)[idx] = (float)((double)base[idx] + sd);
                    if constexpr (OUT_MODE == 1) {
                        const float xn = ((float*)Out_)[idx];
                        const u16 hb = bf16_rne(xn);
                        const size_t fm = (((size_t)(t * BB + b) * (NN / 16) + (n >> 4))
                                           * (CC / 32) + (o >> 5)) * 512
                                        + ((o >> 3) & 3) * 128 + (n & 15) * 8 + (o & 7);
                        OutH[fm] = hb;
                        OutL[fm] = bf16_rne(xn - bf16f(hb));
                    }
                }
                v = v * (1.0 - sd);
            }
        }
    }
}

// ---- kv via MFMA: one wave per (t,b,h); exact 0/1 bf16 spikes ----
__global__ __launch_bounds__(256) void kv_mfma(
    const u16* __restrict__ k_s, const u16* __restrict__ v_s,
    float* __restrict__ kv)
{
    const int lane = threadIdx.x & 63;
    const int wave = threadIdx.x >> 6;
    const int unit = blockIdx.x * 4 + wave;
    const int h = unit & 7;
    const int m = unit >> 3;
    const int lr = lane & 15, lk = lane >> 4;
    const size_t base = ((size_t)m * CC + h * DD) * NN;

    f32x4 acc[2][2];
#pragma unroll
    for (int mt = 0; mt < 2; ++mt)
#pragma unroll
        for (int nt = 0; nt < 2; ++nt)
            acc[mt][nt] = (f32x4){0.f, 0.f, 0.f, 0.f};

#pragma unroll 4
    for (int ks = 0; ks < 32; ++ks) {
        s16x8 a[2], bf[2];
#pragma unroll
        for (int mt = 0; mt < 2; ++mt)
            a[mt] = *(const s16x8*)&k_s[base + (size_t)(mt * 16 + lr) * NN
                                         + ks * 32 + lk * 8];
#pragma unroll
        for (int nt = 0; nt < 2; ++nt)
            bf[nt] = *(const s16x8*)&v_s[base + (size_t)(nt * 16 + lr) * NN
                                          + ks * 32 + lk * 8];
#pragma unroll
        for (int mt = 0; mt < 2; ++mt)
#pragma unroll
            for (int nt = 0; nt < 2; ++nt)
                acc[mt][nt] = __builtin_amdgcn_mfma_f32_16x16x32_bf16(
                    a[mt], bf[nt], acc[mt][nt], 0, 0, 0);
    }
#pragma unroll
    for (int mt = 0; mt < 2; ++mt)
#pragma unroll
        for (int nt = 0; nt < 2; ++nt)
#pragma unroll
            for (int r = 0; r < 4; ++r)
                kv[(size_t)unit * 1024 + (mt * 16 + lk * 4 + r) * 32
                   + nt * 16 + lr] = acc[mt][nt][r];
}

// a = 0.125 * q @ kv -> LIF(0.5); LDS-staged q; writes natural a_s AND FM aT.
__global__ __launch_bounds__(256) void attn_a_lif(
    const u16* __restrict__ q_s, const float* __restrict__ kv,
    u16* __restrict__ a_s, u16* __restrict__ aT)
{
    __shared__ u16 qt[TT][32][64];
    __shared__ float kvs[TT][32][32];
    __shared__ u16 ast[TT][4][512];
    const int tid = threadIdx.x;
    const int n0 = blockIdx.x * 64;
    const int h  = blockIdx.y;
    const int b  = blockIdx.z;

    for (int i = tid; i < TT * 32 * 64 / 4; i += 256) {
        const int t = i >> 9, rem = i & 511;
        const int d = rem >> 4, n4 = rem & 15;
        const size_t g = (((size_t)t * BB + b) * CC + h * DD + d) * NN + n0 + n4 * 4;
        *(ushort4*)&qt[t][d][n4 * 4] = *(const ushort4*)&q_s[g];
    }
    for (int i = tid; i < TT * 32 * 32 / 4; i += 256) {
        const int t = i >> 8, rem = i & 255;
        const int d = rem >> 3, e4 = rem & 7;
        const size_t g = (((size_t)t * BB + b) * HEADS + h) * 1024 + d * 32 + e4 * 4;
        *(float4*)&kvs[t][d][e4 * 4] = *(const float4*)&kv[g];
    }
    __syncthreads();

    const int nl = tid & 63;
    const int eg = tid >> 6;
#pragma unroll
    for (int ei = 0; ei < 8; ++ei) {
        const int e = eg * 8 + ei;
        float val[TT];
#pragma unroll
        for (int t = 0; t < TT; ++t) {
            float s = 0.f;
#pragma unroll 8
            for (int d = 0; d < 32; ++d)
                s += bf16f(qt[t][d][nl]) * kvs[t][d][e];
            val[t] = s * 0.125f;
        }
        float v = 0.f;
#pragma unroll
        for (int t = 0; t < TT; ++t) {
            v = v + (val[t] - v) * 0.5f;
            float s = (v >= 0.5f) ? 1.f : 0.f;
            const u16 sp = (s > 0.5f) ? (u16)0x3F80 : (u16)0;
            a_s[(((size_t)t * BB + b) * CC + h * DD + e) * NN + n0 + nl] = sp;
            ast[t][nl >> 4][((e >> 3) & 3) * 128 + (nl & 15) * 8 + (e & 7)] = sp;
            v = v * (1.f - s);
        }
    }
    __syncthreads();
    for (int i = tid; i < 1024; i += 256) {
        const int t = i >> 8, r2 = i & 255;
        const int ntile = r2 >> 6, pos = (r2 & 63) * 8;
        const size_t gb = (((size_t)(t * BB + b) * (NN / 16) + (n0 / 16 + ntile))
                           * (CC / 32) + h) * 512 + pos;
        *(s16x8*)&aT[gb] = *(const s16x8*)&ast[t][ntile][pos];
    }
}

extern "C" void kernel_launch(void* const* d_in, const int* in_sizes, int n_in,
                              void* d_out, int out_size, void* d_ws, size_t ws_size,
                              hipStream_t stream)
{
    const float* x       = (const float*)d_in[0];
    const float* q_w     = (const float*)d_in[1];
    const float* q_bn    = (const float*)d_in[2];
    const float* k_w     = (const float*)d_in[3];
    const float* k_bn    = (const float*)d_in[4];
    const float* v_w     = (const float*)d_in[5];
    const float* v_bn    = (const float*)d_in[6];
    const float* proj_w  = (const float*)d_in[7];
    const float* proj_b  = (const float*)d_in[8];
    const float* proj_bn = (const float*)d_in[9];
    const float* mlp1_w  = (const float*)d_in[10];
    const float* mlp1_b  = (const float*)d_in[11];
    const float* mlp1_bn = (const float*)d_in[12];
    const float* mlp2_w  = (const float*)d_in[13];
    const float* mlp2_b  = (const float*)d_in[14];
    const float* mlp2_bn = (const float*)d_in[15];

    const size_t SZ = (size_t)TT * BB * CC * NN;   // 8388608
    const size_t U = SZ * 2;                       // 16.75 MB unit
    char* ws = (char*)d_ws;
    u16*   xTh  = (u16*)(ws);
    u16*   xTl  = (u16*)(ws + U);
    u16*   q_s  = (u16*)(ws + 2*U);
    u16*   k_s  = (u16*)(ws + 3*U);
    u16*   v_s  = (u16*)(ws + 4*U);
    u16*   a_s  = (u16*)(ws);              // overlays xTh
    u16*   aT   = (u16*)(ws + U);          // overlays xTl
    float* x_new= (float*)(ws + 2*U);      // overlays q_s,k_s
    u16*   xnTh = (u16*)(ws + 4*U);        // overlays v_s
    u16*   xnTl = (u16*)(ws + 5*U);
    u16*   h1T  = (u16*)(ws + 10*U);
    char* wp = ws + 14*U;
    float* kvb = (float*)wp; wp += (size_t)262144 * 4;
    u16* qh  = (u16*)wp; wp += 65536 * 2;  u16* ql  = (u16*)wp; wp += 65536 * 2;
    u16* kh  = (u16*)wp; wp += 65536 * 2;  u16* kl  = (u16*)wp; wp += 65536 * 2;
    u16* vh  = (u16*)wp; wp += 65536 * 2;  u16* vl  = (u16*)wp; wp += 65536 * 2;
    u16* ph  = (u16*)wp; wp += 65536 * 2;  u16* pl  = (u16*)wp; wp += 65536 * 2;
    u16* m1h = (u16*)wp; wp += 262144 * 2; u16* m1l = (u16*)wp; wp += 262144 * 2;
    u16* m2h = (u16*)wp; wp += 262144 * 2; u16* m2l = (u16*)wp; wp += 262144 * 2;
    float2* bnf = (float2*)wp; wp += 2304 * 8;
    double* bnd = (double*)wp; wp += 2304 * 8;
    u32* cnts = (u32*)wp; wp += 4 * 4;
    u32* list0 = (u32*)wp; wp += FIXCAP * 4;
    u32* list1 = (u32*)wp; wp += FIXCAP * 4;
    u32* list2 = (u32*)wp; wp += FIXCAP * 4;
    u32* list3 = (u32*)wp;

    dim3 blk(256);

    // prep (2 dispatches): all weights -> FM hi/lo; BN consts + counter zero
    prep_weights_all<<<dim3(384), blk, 0, stream>>>(
        q_w, k_w, v_w, proj_w, mlp1_w, mlp2_w,
        qh, ql, kh, kl, vh, vl, ph, pl, m1h, m1l, m2h, m2l);
    prep_bn<<<dim3(9), blk, 0, stream>>>(q_bn, k_bn, v_bn, proj_bn, mlp1_bn,
                                         mlp2_bn, proj_b, mlp1_b, mlp2_b,
                                         bnf, bnd, cnts);
    trans_split_fm<256, 1024><<<dim3(16, 4, 32), blk, 0, stream>>>(x, xTh, xTl);

    // qkv: FM x -> bf16 spike trains [c][n]
    conv_kernel<true, 256, 0, true, 256><<<dim3(12, 16, 8), blk, 0, stream>>>(
        xTh, xTl, qh, ql, kh, kl, vh, vl, bnf, q_s, k_s, v_s,
        nullptr, nullptr, nullptr, cnts + 0, list0);
    fixup_kernel<false, false, 256, 0, 256><<<dim3(1024), dim3(64), 0, stream>>>(
        cnts + 0, list0, x, q_w, k_w, v_w, q_bn, k_bn, v_bn, nullptr, bnd,
        q_s, k_s, v_s, nullptr, nullptr, nullptr);

    // attention (exact): kv via MFMA, then a + LIF (writes a_s AND FM aT)
    kv_mfma<<<dim3(64), blk, 0, stream>>>(k_s, v_s, kvb);
    attn_a_lif<<<dim3(16, 8, 8), blk, 0, stream>>>(q_s, kvb, a_s, aT);

    // proj: FM a -> x_new f32 [c][n] + fused FM hi/lo planes (+x base)
    conv_kernel<false, 256, 1, false, 256><<<dim3(4, 16, 8), blk, 0, stream>>>(
        aT, nullptr, ph, pl, nullptr, nullptr, nullptr, nullptr,
        bnf + 768, x_new, nullptr, nullptr, xnTh, xnTl, x, cnts + 1, list1);
    fixup_kernel<true, false, 256, 1, 256><<<dim3(1024), dim3(64), 0, stream>>>(
        cnts + 1, list1, a_s, proj_w, nullptr, nullptr, proj_bn, nullptr,
        nullptr, proj_b, bnd + 768, x_new, nullptr, nullptr, xnTh, xnTl, x);

    // mlp1: FM x_new -> h1T FM spikes DIRECTLY
    conv_kernel<true, 256, 2, false, 1024><<<dim3(16, 16, 8), blk, 0, stream>>>(
        xnTh, xnTl, m1h, m1l, nullptr, nullptr, nullptr, nullptr,
        bnf + 1024, h1T, nullptr, nullptr, nullptr, nullptr, nullptr,
        cnts + 2, list2);
    fixup_kernel<false, false, 256, 2, 1024><<<dim3(1024), dim3(64), 0, stream>>>(
        cnts + 2, list2, x_new, mlp1_w, nullptr, nullptr, mlp1_bn, nullptr,
        nullptr, mlp1_b, bnd + 1024, h1T, nullptr, nullptr, nullptr, nullptr,
        nullptr);

    // mlp2: FM h1 -> d_out (+x_new base)
    conv_kernel<false, 1024, 3, false, 256><<<dim3(4, 16, 8), blk, 0, stream>>>(
        h1T, nullptr, m2h, m2l, nullptr, nullptr, nullptr, nullptr,
        bnf + 2048, d_out, nullptr, nullptr, nullptr, nullptr, x_new,
        cnts + 3, list3);
    fixup_kernel<true, true, 1024, 3, 256><<<dim3(1024), dim3(64), 0, stream>>>(
        cnts + 3, list3, h1T, mlp2_w, nullptr, nullptr, mlp2_bn, nullptr,
        nullptr, mlp2_b, bnd + 2048, d_out, nullptr, nullptr, nullptr, nullptr,
        x_new);
}